// Round 5
// baseline (396.180 us; speedup 1.0000x reference)
//
#include <hip/hip_runtime.h>
#include <hip/hip_bf16.h>

#define N_NODES 79
#define RAW_FEAT 26
#define D_IN 32
#define D_OUT 64
#define HIDDEN 256
#define N_EDGES 3000
#define BATCH 256
#define M_ROWS (BATCH * N_NODES)   // 20224
#define K1PAD 112                  // GEMM1 K padded to 7 chunks of 16

// ---------------------------------------------------------------------------
// k_prep: blocks 0-7: W1 [256][97] -> W1t [112][256] (rows 97..111 zero);
//         blocks 8-23: W2 [256][256] -> W2t [256][256]; block 24: CSR by dst.
// ---------------------------------------------------------------------------
__global__ __launch_bounds__(256) void k_prep(
    const float* __restrict__ W1, const float* __restrict__ W2,
    const int* __restrict__ ei, const float* __restrict__ ew,
    float* __restrict__ W1t, float* __restrict__ W2t,
    int* __restrict__ rp, int* __restrict__ csr_src,
    int* __restrict__ csr_dst, float* __restrict__ csr_ew)
{
    __shared__ float tile[64][65];
    __shared__ int cnt[N_NODES];
    __shared__ int base[N_NODES + 1];
    const int tid = threadIdx.x, bid = blockIdx.x;

    if (bid < 24) {
        const float* in; float* out; int C, Kpad, kb, rb;
        if (bid < 8) { in = W1; out = W1t; C = 97; Kpad = K1PAD;
                       kb = (bid & 1) * 64; rb = (bid >> 1) * 64; }
        else         { int b = bid - 8; in = W2; out = W2t; C = 256; Kpad = 256;
                       kb = (b & 3) * 64; rb = (b >> 2) * 64; }
        for (int i = tid; i < 4096; i += 256) {
            int rr = i >> 6, kk = i & 63;
            int r = rb + rr, k = kb + kk;
            tile[rr][kk] = (k < C) ? in[r * C + k] : 0.f;
        }
        __syncthreads();
        for (int i = tid; i < 4096; i += 256) {
            int kk = i >> 6, rr = i & 63;
            int k = kb + kk, r = rb + rr;
            if (k < Kpad) out[(size_t)k * HIDDEN + r] = tile[rr][kk];
        }
        return;
    }

    // ---- CSR build (one block)
    if (tid < N_NODES) cnt[tid] = 0;
    __syncthreads();
    for (int e = tid; e < N_EDGES; e += 256) atomicAdd(&cnt[ei[N_EDGES + e]], 1);
    __syncthreads();
    if (tid == 0) {
        int run = 0;
        for (int n = 0; n < N_NODES; ++n) { base[n] = run; run += cnt[n]; }
        base[N_NODES] = run;
    }
    __syncthreads();
    if (tid < N_NODES + 1) rp[tid] = base[tid];
    if (tid < N_NODES) cnt[tid] = base[tid];
    __syncthreads();
    for (int e = tid; e < N_EDGES; e += 256) {
        int d = ei[N_EDGES + e];
        int p = atomicAdd(&cnt[d], 1);
        csr_src[p] = ei[e];
        csr_dst[p] = d;
        csr_ew[p]  = ew[e];
    }
}

// ---------------------------------------------------------------------------
// K1: TransformerConv per batch element. Dense formulation:
//   S = Q K^T (register-tiled LDS GEMM), alpha from S gather,
//   softmax via per-node owner scans (no atomics),
//   A[dst][src] dense scatter, agg = A V (dense GEMM).
// ---------------------------------------------------------------------------
__global__ __launch_bounds__(512) void k1_conv(
    const float* __restrict__ state, const float* __restrict__ pos,
    const int* __restrict__ rp_g, const int* __restrict__ csrc_g,
    const int* __restrict__ cdst_g, const float* __restrict__ cew_g,
    const float* __restrict__ Wq, const float* __restrict__ bq,
    const float* __restrict__ Wk, const float* __restrict__ bk,
    const float* __restrict__ Wv, const float* __restrict__ bv,
    const float* __restrict__ We, const float* __restrict__ Wsk,
    const float* __restrict__ bsk,
    float* __restrict__ out1_ws, float* __restrict__ ta_ws)
{
    __shared__ __align__(16) float qs [80 * 68];   // row 79 zero pad
    __shared__ __align__(16) float kss[80 * 68];
    __shared__ __align__(16) float vss[80 * 68];
    __shared__ __align__(16) float o1s[N_NODES * 68];
    __shared__ __align__(16) float xs[N_NODES * 32];
    __shared__ __align__(16) float SA[80 * 80];    // S then (zeroed) A
    __shared__ __align__(16) float alpha[N_EDGES];
    __shared__ __align__(16) float ewc[N_EDGES];
    __shared__ unsigned short srcs[N_EDGES], dsts[N_EDGES];
    __shared__ __align__(16) float eW[64];
    __shared__ int   rp_s[80];
    __shared__ float qWe[80], csum_s[80];

    const int b = blockIdx.x, tid = threadIdx.x;

    // ---- stage
    for (int t = tid; t < N_NODES * 32; t += 512) {
        int n = t >> 5, c = t & 31;
        xs[t] = (c < RAW_FEAT) ? state[(b * N_NODES + n) * RAW_FEAT + c]
                               : pos[n * 6 + (c - RAW_FEAT)];
    }
    for (int t = tid; t < N_EDGES; t += 512) {
        srcs[t] = (unsigned short)csrc_g[t];
        dsts[t] = (unsigned short)cdst_g[t];
        ewc[t]  = cew_g[t];
    }
    if (tid < 64) eW[tid] = We[tid];
    if (tid < 80) rp_s[tid] = rp_g[tid];
    for (int t = tid; t < 68; t += 512) {          // zero pad row 79
        qs[79 * 68 + t] = 0.f; kss[79 * 68 + t] = 0.f; vss[79 * 68 + t] = 0.f;
    }
    __syncthreads();

    // ---- QKVS: per (n,d) dot over 32 channels (verified in round 3)
    {
        const float4* xs4 = (const float4*)xs;
        const float4* Wq4 = (const float4*)Wq;
        const float4* Wk4 = (const float4*)Wk;
        const float4* Wv4 = (const float4*)Wv;
        const float4* Ws4 = (const float4*)Wsk;
        for (int t = tid; t < N_NODES * 64; t += 512) {
            int n = t >> 6, d = t & 63;
            float aq = bq[d], ak = bk[d], av = bv[d], ask = bsk[d];
            #pragma unroll
            for (int c4 = 0; c4 < 8; ++c4) {
                float4 xv = xs4[n * 8 + c4];
                float4 wq = Wq4[d * 8 + c4];
                float4 wk = Wk4[d * 8 + c4];
                float4 wv = Wv4[d * 8 + c4];
                float4 wsv = Ws4[d * 8 + c4];
                aq += xv.x * wq.x + xv.y * wq.y + xv.z * wq.z + xv.w * wq.w;
                ak += xv.x * wk.x + xv.y * wk.y + xv.z * wk.z + xv.w * wk.w;
                av += xv.x * wv.x + xv.y * wv.y + xv.z * wv.z + xv.w * wv.w;
                ask += xv.x * wsv.x + xv.y * wsv.y + xv.z * wsv.z + xv.w * wsv.w;
            }
            qs [n * 68 + d] = aq;
            kss[n * 68 + d] = ak;
            vss[n * 68 + d] = av;
            o1s[n * 68 + d] = ask;
        }
        if (tid == 511) {
            float s = 0.f;
            #pragma unroll
            for (int n = 0; n < N_NODES; ++n) s += xs[n * 32 + 1];
            ta_ws[b] = s;
        }
    }
    __syncthreads();

    // ---- qWe[n] = dot(q[n], We)
    if (tid < N_NODES) {
        const float4* q4 = (const float4*)(qs + tid * 68);
        const float4* e4 = (const float4*)eW;
        float s = 0.f;
        #pragma unroll
        for (int i = 0; i < 16; ++i) {
            float4 a = q4[i], e = e4[i];
            s += a.x * e.x + a.y * e.y + a.z * e.z + a.w * e.w;
        }
        qWe[tid] = s;
    }
    __syncthreads();

    // ---- dense S = Q K^T  (thread tile 5 rows x 3 cols)
    {
        const int rg = tid >> 5, cgp = tid & 31;
        const int r0 = rg * 5;                       // 0..75
        int c0 = cgp * 3; if (c0 > 76) c0 = 76;      // duplicates benign
        float acc[5][3] = {};
        const float4* q4p = (const float4*)qs;
        const float4* k4p = (const float4*)kss;
        for (int k4 = 0; k4 < 16; ++k4) {
            float4 qv[5], kv[3];
            #pragma unroll
            for (int i = 0; i < 5; ++i) qv[i] = q4p[(r0 + i) * 17 + k4];
            #pragma unroll
            for (int j = 0; j < 3; ++j) kv[j] = k4p[(c0 + j) * 17 + k4];
            #pragma unroll
            for (int i = 0; i < 5; ++i)
                #pragma unroll
                for (int j = 0; j < 3; ++j)
                    acc[i][j] += qv[i].x * kv[j].x + qv[i].y * kv[j].y
                               + qv[i].z * kv[j].z + qv[i].w * kv[j].w;
        }
        #pragma unroll
        for (int i = 0; i < 5; ++i)
            #pragma unroll
            for (int j = 0; j < 3; ++j) {
                int r = r0 + i, c = c0 + j;
                if (r < N_NODES && c < N_NODES) SA[r * 80 + c] = acc[i][j];
            }
    }
    __syncthreads();

    // ---- alpha per edge (gather from dense S)
    for (int t = tid; t < N_EDGES; t += 512) {
        int s = srcs[t], d = dsts[t];
        alpha[t] = 0.125f * (SA[d * 80 + s] + ewc[t] * qWe[d]);
    }
    __syncthreads();

    // ---- S dead: zero SA so it can accumulate A
    for (int t = tid; t < 6400; t += 512) SA[t] = 0.f;
    __syncthreads();

    // ---- per-node owner: max -> exp/den/csum -> A scatter (race-free)
    if (tid < N_NODES) {
        int e0 = rp_s[tid], e1 = rp_s[tid + 1];
        float m = -1e30f;
        for (int e = e0; e < e1; ++e) m = fmaxf(m, alpha[e]);
        float s = 0.f, cs = 0.f;
        for (int e = e0; e < e1; ++e) {
            float ex = expf(alpha[e] - m);
            alpha[e] = ex;
            s += ex; cs += ex * ewc[e];
        }
        float rden = 1.f / (s + 1e-16f);
        csum_s[tid] = cs * rden;
        float* Ar = SA + tid * 80;
        for (int e = e0; e < e1; ++e) Ar[srcs[e]] += alpha[e] * rden;
    }
    __syncthreads();

    // ---- dense agg = A V (thread tile 3 rows x 4 cols) + epilogue
    {
        const int rowg = tid >> 4, colg = tid & 15;
        int n0 = rowg * 3; if (n0 > 76) n0 = 76;     // duplicates benign
        float acc[3][4] = {};
        const float4* A4  = (const float4*)SA;
        const float4* v4p = (const float4*)vss;
        for (int s4 = 0; s4 < 20; ++s4) {
            float4 av[3];
            #pragma unroll
            for (int i = 0; i < 3; ++i) av[i] = A4[(n0 + i) * 20 + s4];
            #pragma unroll
            for (int ss = 0; ss < 4; ++ss) {
                float4 vv = v4p[(s4 * 4 + ss) * 17 + colg];
                #pragma unroll
                for (int i = 0; i < 3; ++i) {
                    float w = ((const float*)&av[i])[ss];
                    acc[i][0] += w * vv.x; acc[i][1] += w * vv.y;
                    acc[i][2] += w * vv.z; acc[i][3] += w * vv.w;
                }
            }
        }
        const float4* o4 = (const float4*)o1s;
        const float4* e4 = (const float4*)eW;
        float4 ev = e4[colg];
        #pragma unroll
        for (int i = 0; i < 3; ++i) {
            int n = n0 + i;
            if (n < N_NODES) {
                float4 sk = o4[n * 17 + colg];
                float cs = csum_s[n];
                float4 r;
                r.x = fmaxf(sk.x + acc[i][0] + cs * ev.x, 0.f);
                r.y = fmaxf(sk.y + acc[i][1] + cs * ev.y, 0.f);
                r.z = fmaxf(sk.z + acc[i][2] + cs * ev.z, 0.f);
                r.w = fmaxf(sk.w + acc[i][3] + cs * ev.w, 0.f);
                ((float4*)out1_ws)[((size_t)b * N_NODES + n) * 16 + colg] = r;
            }
        }
    }
}

// ---------------------------------------------------------------------------
// K23: fused MLP. 16 rows/block, 1264 blocks, thread = 4 rows x 4 cols.
// W staged in 16-k-row LDS chunks with register prefetch; A-tile reads are
// wave-uniform broadcasts; Ws reads are 64 consecutive f4 (conflict-free).
// LN per-row entirely within one wave via shfl_xor.
// ---------------------------------------------------------------------------
__global__ __launch_bounds__(256, 4) void k23_mlp(
    const float* __restrict__ state, const float* __restrict__ pos,
    const float* __restrict__ out1_ws, const float* __restrict__ ta_ws,
    const float* __restrict__ W1t, const float* __restrict__ b1,
    const float* __restrict__ g1, const float* __restrict__ be1,
    const float* __restrict__ W2t, const float* __restrict__ b2,
    const float* __restrict__ g2, const float* __restrict__ be2,
    const float* __restrict__ W3, const float* __restrict__ b3,
    float* __restrict__ conc_ws)
{
    __shared__ __align__(16) float A1[16 * K1PAD];   // [r][k] 7 KB
    __shared__ __align__(16) float A2[16 * 256];     // [r][k] 16 KB
    __shared__ __align__(16) float Ws[16 * 256];     // [kloc][c] 16 KB

    const int tid = threadIdx.x;
    const int lane = tid & 63;          // col group: cols 4*lane..+3
    const int wv = tid >> 6;            // wave: rows 4*wv..+3
    const int m0 = blockIdx.x * 16;

    const float4* W1t4 = (const float4*)W1t;
    const float4* W2t4 = (const float4*)W2t;
    const float4* A1r4 = (const float4*)A1;
    const float4* A2r4 = (const float4*)A2;
    float4* Ws4 = (float4*)Ws;
    const float4* Wsc4 = (const float4*)Ws;

    // ---- stage A1 [16][112]
    for (int t = tid; t < 16 * K1PAD; t += 256) {
        int r = t / K1PAD, k = t - r * K1PAD;
        int m = m0 + r;
        float v = 0.f;
        if (k < 64)       v = out1_ws[m * 64 + k];
        else if (k == 64) v = ta_ws[m / N_NODES];
        else if (k < 91)  v = state[m * RAW_FEAT + (k - 65)];
        else if (k < 97)  { int n = m - (m / N_NODES) * N_NODES;
                            v = pos[n * 6 + (k - 91)]; }
        A1[t] = v;
    }

    float4 pre[4];
    #pragma unroll
    for (int i = 0; i < 4; ++i) pre[i] = W1t4[(wv + 4 * i) * 64 + lane];
    __syncthreads();

    float acc[4][4] = {};

    // ---- GEMM1: 7 chunks of K=16
    for (int ch = 0; ch < 7; ++ch) {
        #pragma unroll
        for (int i = 0; i < 4; ++i) Ws4[(wv + 4 * i) * 64 + lane] = pre[i];
        __syncthreads();
        if (ch < 6) {
            #pragma unroll
            for (int i = 0; i < 4; ++i)
                pre[i] = W1t4[((ch + 1) * 16 + wv + 4 * i) * 64 + lane];
        }
        for (int kq = 0; kq < 4; ++kq) {
            float4 a4[4];
            #pragma unroll
            for (int rr = 0; rr < 4; ++rr)
                a4[rr] = A1r4[(4 * wv + rr) * 28 + ch * 4 + kq];
            #pragma unroll
            for (int kk = 0; kk < 4; ++kk) {
                float4 w = Wsc4[(kq * 4 + kk) * 64 + lane];
                #pragma unroll
                for (int rr = 0; rr < 4; ++rr) {
                    float av = ((const float*)&a4[rr])[kk];
                    acc[rr][0] += av * w.x; acc[rr][1] += av * w.y;
                    acc[rr][2] += av * w.z; acc[rr][3] += av * w.w;
                }
            }
        }
        __syncthreads();
    }

    // prefetch W2 chunk 0 (hide under LN1)
    #pragma unroll
    for (int i = 0; i < 4; ++i) pre[i] = W2t4[(wv + 4 * i) * 64 + lane];

    // ---- bias + LN1 + leaky -> A2
    {
        float4 bv = ((const float4*)b1)[lane];
        float4 gv = ((const float4*)g1)[lane];
        float4 ev = ((const float4*)be1)[lane];
        #pragma unroll
        for (int rr = 0; rr < 4; ++rr) {
            float v0 = acc[rr][0] + bv.x, v1 = acc[rr][1] + bv.y;
            float v2 = acc[rr][2] + bv.z, v3 = acc[rr][3] + bv.w;
            float sm = v0 + v1 + v2 + v3;
            float sq = v0 * v0 + v1 * v1 + v2 * v2 + v3 * v3;
            #pragma unroll
            for (int off = 32; off >= 1; off >>= 1) {
                sm += __shfl_xor(sm, off, 64);
                sq += __shfl_xor(sq, off, 64);
            }
            float mu = sm * (1.f / 256.f);
            float rstd = rsqrtf(sq * (1.f / 256.f) - mu * mu + 1e-5f);
            float4 yv;
            yv.x = (v0 - mu) * rstd * gv.x + ev.x;
            yv.y = (v1 - mu) * rstd * gv.y + ev.y;
            yv.z = (v2 - mu) * rstd * gv.z + ev.z;
            yv.w = (v3 - mu) * rstd * gv.w + ev.w;
            yv.x = yv.x > 0.f ? yv.x : 0.01f * yv.x;
            yv.y = yv.y > 0.f ? yv.y : 0.01f * yv.y;
            yv.z = yv.z > 0.f ? yv.z : 0.01f * yv.z;
            yv.w = yv.w > 0.f ? yv.w : 0.01f * yv.w;
            ((float4*)A2)[(4 * wv + rr) * 64 + lane] = yv;
            acc[rr][0] = 0.f; acc[rr][1] = 0.f; acc[rr][2] = 0.f; acc[rr][3] = 0.f;
        }
    }
    __syncthreads();

    // ---- GEMM2: 16 chunks of K=16
    for (int ch = 0; ch < 16; ++ch) {
        #pragma unroll
        for (int i = 0; i < 4; ++i) Ws4[(wv + 4 * i) * 64 + lane] = pre[i];
        __syncthreads();
        if (ch < 15) {
            #pragma unroll
            for (int i = 0; i < 4; ++i)
                pre[i] = W2t4[((ch + 1) * 16 + wv + 4 * i) * 64 + lane];
        }
        for (int kq = 0; kq < 4; ++kq) {
            float4 a4[4];
            #pragma unroll
            for (int rr = 0; rr < 4; ++rr)
                a4[rr] = A2r4[(4 * wv + rr) * 64 + ch * 4 + kq];
            #pragma unroll
            for (int kk = 0; kk < 4; ++kk) {
                float4 w = Wsc4[(kq * 4 + kk) * 64 + lane];
                #pragma unroll
                for (int rr = 0; rr < 4; ++rr) {
                    float av = ((const float*)&a4[rr])[kk];
                    acc[rr][0] += av * w.x; acc[rr][1] += av * w.y;
                    acc[rr][2] += av * w.z; acc[rr][3] += av * w.w;
                }
            }
        }
        __syncthreads();
    }

    // ---- bias + LN2 + leaky + W3 dot + softplus
    {
        float4 bv = ((const float4*)b2)[lane];
        float4 gv = ((const float4*)g2)[lane];
        float4 ev = ((const float4*)be2)[lane];
        float4 w3 = ((const float4*)W3)[lane];
        float bb3 = b3[0];
        #pragma unroll
        for (int rr = 0; rr < 4; ++rr) {
            float v0 = acc[rr][0] + bv.x, v1 = acc[rr][1] + bv.y;
            float v2 = acc[rr][2] + bv.z, v3 = acc[rr][3] + bv.w;
            float sm = v0 + v1 + v2 + v3;
            float sq = v0 * v0 + v1 * v1 + v2 * v2 + v3 * v3;
            #pragma unroll
            for (int off = 32; off >= 1; off >>= 1) {
                sm += __shfl_xor(sm, off, 64);
                sq += __shfl_xor(sq, off, 64);
            }
            float mu = sm * (1.f / 256.f);
            float rstd = rsqrtf(sq * (1.f / 256.f) - mu * mu + 1e-5f);
            float z0 = (v0 - mu) * rstd * gv.x + ev.x;
            float z1 = (v1 - mu) * rstd * gv.y + ev.y;
            float z2 = (v2 - mu) * rstd * gv.z + ev.z;
            float z3 = (v3 - mu) * rstd * gv.w + ev.w;
            z0 = z0 > 0.f ? z0 : 0.01f * z0;
            z1 = z1 > 0.f ? z1 : 0.01f * z1;
            z2 = z2 > 0.f ? z2 : 0.01f * z2;
            z3 = z3 > 0.f ? z3 : 0.01f * z3;
            float part = z0 * w3.x + z1 * w3.y + z2 * w3.z + z3 * w3.w;
            #pragma unroll
            for (int off = 32; off >= 1; off >>= 1)
                part += __shfl_xor(part, off, 64);
            if (lane == 0) {
                float x = part + bb3;
                float sp = fmaxf(x, 0.f) + log1pf(expf(-fabsf(x)));
                conc_ws[m0 + 4 * wv + rr] = sp;
            }
        }
    }
}

// ---------------------------------------------------------------------------
// K4: action = conc / (sum_n conc + 1e-20), per batch
// ---------------------------------------------------------------------------
__global__ __launch_bounds__(128) void k4_norm(
    const float* __restrict__ conc_ws, float* __restrict__ out)
{
    __shared__ float red[128];
    const int b = blockIdx.x, tid = threadIdx.x;
    float v = 0.f;
    if (tid < N_NODES) v = conc_ws[b * N_NODES + tid];
    red[tid] = v;
    __syncthreads();
    for (int off = 64; off >= 1; off >>= 1) {
        if (tid < off) red[tid] += red[tid + off];
        __syncthreads();
    }
    float s = red[0];
    if (tid < N_NODES) out[b * N_NODES + tid] = v / (s + 1e-20f);
}

extern "C" void kernel_launch(void* const* d_in, const int* in_sizes, int n_in,
                              void* d_out, int out_size, void* d_ws, size_t ws_size,
                              hipStream_t stream) {
    const float* state = (const float*)d_in[0];
    const float* pos   = (const float*)d_in[1];
    const float* ew    = (const float*)d_in[2];
    const float* Wq  = (const float*)d_in[3];  const float* bq  = (const float*)d_in[4];
    const float* Wk  = (const float*)d_in[5];  const float* bk  = (const float*)d_in[6];
    const float* Wv  = (const float*)d_in[7];  const float* bv  = (const float*)d_in[8];
    const float* We  = (const float*)d_in[9];
    const float* Wsk = (const float*)d_in[10]; const float* bsk = (const float*)d_in[11];
    const float* W1  = (const float*)d_in[12]; const float* b1  = (const float*)d_in[13];
    const float* g1  = (const float*)d_in[14]; const float* be1 = (const float*)d_in[15];
    const float* W2  = (const float*)d_in[16]; const float* b2  = (const float*)d_in[17];
    const float* g2  = (const float*)d_in[18]; const float* be2 = (const float*)d_in[19];
    const float* W3  = (const float*)d_in[20]; const float* b3  = (const float*)d_in[21];
    const int*   ei  = (const int*)d_in[22];

    float* ws   = (float*)d_ws;
    float* ta   = ws;                                  // 256
    float* out1 = ws + 256;                            // M*64
    float* conc = out1 + (size_t)M_ROWS * 64;          // M
    float* W1t  = conc + M_ROWS;                       // 112*256
    float* W2t  = W1t + K1PAD * HIDDEN;                // 256*256
    int*   rp   = (int*)(W2t + HIDDEN * HIDDEN);       // 80
    int*   csrc = rp + 80;                             // 3000
    int*   cdst = csrc + N_EDGES;                      // 3000
    float* cew  = (float*)(cdst + N_EDGES);            // 3000
    float* out  = (float*)d_out;

    k_prep<<<dim3(25), dim3(256), 0, stream>>>(
        W1, W2, ei, ew, W1t, W2t, rp, csrc, cdst, cew);
    k1_conv<<<dim3(BATCH), dim3(512), 0, stream>>>(
        state, pos, rp, csrc, cdst, cew,
        Wq, bq, Wk, bk, Wv, bv, We, Wsk, bsk, out1, ta);
    k23_mlp<<<dim3(M_ROWS / 16), dim3(256), 0, stream>>>(
        state, pos, out1, ta, W1t, b1, g1, be1,
        W2t, b2, g2, be2, W3, b3, conc);
    k4_norm<<<dim3(BATCH), dim3(128), 0, stream>>>(conc, out);
}

// Round 6
// 246.509 us; speedup vs baseline: 1.6072x; 1.6072x over previous
//
#include <hip/hip_runtime.h>
#include <hip/hip_bf16.h>

#define N_NODES 79
#define RAW_FEAT 26
#define D_IN 32
#define D_OUT 64
#define HIDDEN 256
#define N_EDGES 3000
#define BATCH 256
#define M_ROWS (BATCH * N_NODES)   // 20224
#define K1PAD 112                  // GEMM1 K padded to 7 chunks of 16

// ---------------------------------------------------------------------------
// k_prep: blocks 0-7: W1 [256][97] -> W1t [112][256] (rows 97..111 zero);
//         blocks 8-23: W2 [256][256] -> W2t [256][256]; block 24: CSR by dst.
// ---------------------------------------------------------------------------
__global__ __launch_bounds__(256) void k_prep(
    const float* __restrict__ W1, const float* __restrict__ W2,
    const int* __restrict__ ei, const float* __restrict__ ew,
    float* __restrict__ W1t, float* __restrict__ W2t,
    int* __restrict__ rp, int* __restrict__ csr_src,
    int* __restrict__ csr_dst, float* __restrict__ csr_ew)
{
    __shared__ float tile[64][65];
    __shared__ int cnt[N_NODES];
    __shared__ int base[N_NODES + 1];
    const int tid = threadIdx.x, bid = blockIdx.x;

    if (bid < 24) {
        const float* in; float* out; int C, Kpad, kb, rb;
        if (bid < 8) { in = W1; out = W1t; C = 97; Kpad = K1PAD;
                       kb = (bid & 1) * 64; rb = (bid >> 1) * 64; }
        else         { int b = bid - 8; in = W2; out = W2t; C = 256; Kpad = 256;
                       kb = (b & 3) * 64; rb = (b >> 2) * 64; }
        for (int i = tid; i < 4096; i += 256) {
            int rr = i >> 6, kk = i & 63;
            int r = rb + rr, k = kb + kk;
            tile[rr][kk] = (k < C) ? in[r * C + k] : 0.f;
        }
        __syncthreads();
        for (int i = tid; i < 4096; i += 256) {
            int kk = i >> 6, rr = i & 63;
            int k = kb + kk, r = rb + rr;
            if (k < Kpad) out[(size_t)k * HIDDEN + r] = tile[rr][kk];
        }
        return;
    }

    // ---- CSR build (one block)
    if (tid < N_NODES) cnt[tid] = 0;
    __syncthreads();
    for (int e = tid; e < N_EDGES; e += 256) atomicAdd(&cnt[ei[N_EDGES + e]], 1);
    __syncthreads();
    if (tid == 0) {
        int run = 0;
        for (int n = 0; n < N_NODES; ++n) { base[n] = run; run += cnt[n]; }
        base[N_NODES] = run;
    }
    __syncthreads();
    if (tid < N_NODES + 1) rp[tid] = base[tid];
    if (tid < N_NODES) cnt[tid] = base[tid];
    __syncthreads();
    for (int e = tid; e < N_EDGES; e += 256) {
        int d = ei[N_EDGES + e];
        int p = atomicAdd(&cnt[d], 1);
        csr_src[p] = ei[e];
        csr_dst[p] = d;
        csr_ew[p]  = ew[e];
    }
}

// dot-product accumulate, member access only (NO address-taking -> no scratch)
#define DOT4(S, Aa, Bb) S += Aa.x * Bb.x + Aa.y * Bb.y + Aa.z * Bb.z + Aa.w * Bb.w;

// ---------------------------------------------------------------------------
// K1: TransformerConv per batch element. Dense formulation:
//   S = Q K^T, alpha gather, per-node owner softmax scans (race-free),
//   A[dst][src] dense scatter, agg = A V. All vector ops via .x/.y/.z/.w.
// ---------------------------------------------------------------------------
__global__ __launch_bounds__(512) void k1_conv(
    const float* __restrict__ state, const float* __restrict__ pos,
    const int* __restrict__ rp_g, const int* __restrict__ csrc_g,
    const int* __restrict__ cdst_g, const float* __restrict__ cew_g,
    const float* __restrict__ Wq, const float* __restrict__ bq,
    const float* __restrict__ Wk, const float* __restrict__ bk,
    const float* __restrict__ Wv, const float* __restrict__ bv,
    const float* __restrict__ We, const float* __restrict__ Wsk,
    const float* __restrict__ bsk,
    float* __restrict__ out1_ws, float* __restrict__ ta_ws)
{
    __shared__ __align__(16) float qs [80 * 68];   // row 79 zero pad
    __shared__ __align__(16) float kss[80 * 68];
    __shared__ __align__(16) float vss[80 * 68];
    __shared__ __align__(16) float o1s[N_NODES * 68];
    __shared__ __align__(16) float xs[N_NODES * 32];
    __shared__ __align__(16) float SA[80 * 80];    // S then (zeroed) A
    __shared__ __align__(16) float alpha[N_EDGES];
    __shared__ __align__(16) float ewc[N_EDGES];
    __shared__ unsigned short srcs[N_EDGES], dsts[N_EDGES];
    __shared__ __align__(16) float eW[64];
    __shared__ int   rp_s[80];
    __shared__ float qWe[80], csum_s[80];

    const int b = blockIdx.x, tid = threadIdx.x;

    // ---- stage
    for (int t = tid; t < N_NODES * 32; t += 512) {
        int n = t >> 5, c = t & 31;
        xs[t] = (c < RAW_FEAT) ? state[(b * N_NODES + n) * RAW_FEAT + c]
                               : pos[n * 6 + (c - RAW_FEAT)];
    }
    for (int t = tid; t < N_EDGES; t += 512) {
        srcs[t] = (unsigned short)csrc_g[t];
        dsts[t] = (unsigned short)cdst_g[t];
        ewc[t]  = cew_g[t];
    }
    if (tid < 64) eW[tid] = We[tid];
    if (tid < 80) rp_s[tid] = rp_g[tid];
    for (int t = tid; t < 68; t += 512) {          // zero pad row 79
        qs[79 * 68 + t] = 0.f; kss[79 * 68 + t] = 0.f; vss[79 * 68 + t] = 0.f;
    }
    __syncthreads();

    // ---- QKVS: per (n,d) dot over 32 channels (member access only)
    {
        const float4* xs4 = (const float4*)xs;
        const float4* Wq4 = (const float4*)Wq;
        const float4* Wk4 = (const float4*)Wk;
        const float4* Wv4 = (const float4*)Wv;
        const float4* Ws4 = (const float4*)Wsk;
        for (int t = tid; t < N_NODES * 64; t += 512) {
            int n = t >> 6, d = t & 63;
            float aq = bq[d], ak = bk[d], av = bv[d], ask = bsk[d];
            #pragma unroll
            for (int c4 = 0; c4 < 8; ++c4) {
                float4 xv = xs4[n * 8 + c4];
                float4 wq = Wq4[d * 8 + c4];
                float4 wk = Wk4[d * 8 + c4];
                float4 wv = Wv4[d * 8 + c4];
                float4 wsv = Ws4[d * 8 + c4];
                DOT4(aq, xv, wq)
                DOT4(ak, xv, wk)
                DOT4(av, xv, wv)
                DOT4(ask, xv, wsv)
            }
            qs [n * 68 + d] = aq;
            kss[n * 68 + d] = ak;
            vss[n * 68 + d] = av;
            o1s[n * 68 + d] = ask;
        }
        if (tid == 511) {
            float s = 0.f;
            #pragma unroll
            for (int n = 0; n < N_NODES; ++n) s += xs[n * 32 + 1];
            ta_ws[b] = s;
        }
    }
    __syncthreads();

    // ---- qWe[n] = dot(q[n], We)
    if (tid < N_NODES) {
        const float4* q4 = (const float4*)(qs + tid * 68);
        const float4* e4 = (const float4*)eW;
        float s = 0.f;
        #pragma unroll
        for (int i = 0; i < 16; ++i) {
            float4 a = q4[i], e = e4[i];
            DOT4(s, a, e)
        }
        qWe[tid] = s;
    }
    __syncthreads();

    // ---- dense S = Q K^T: 5 rows x 3 cols per thread, 15 NAMED accumulators
    {
        const int rg = tid >> 5, cgp = tid & 31;
        const int r0 = rg * 5;                       // 0..75 (rows to 79 = pad)
        int c0 = cgp * 3; if (c0 > 76) c0 = 76;      // duplicates benign
        float s00 = 0, s01 = 0, s02 = 0;
        float s10 = 0, s11 = 0, s12 = 0;
        float s20 = 0, s21 = 0, s22 = 0;
        float s30 = 0, s31 = 0, s32 = 0;
        float s40 = 0, s41 = 0, s42 = 0;
        const float4* q4p = (const float4*)qs;
        const float4* k4p = (const float4*)kss;
        for (int k4 = 0; k4 < 16; ++k4) {
            float4 q0 = q4p[(r0 + 0) * 17 + k4];
            float4 q1 = q4p[(r0 + 1) * 17 + k4];
            float4 q2 = q4p[(r0 + 2) * 17 + k4];
            float4 q3 = q4p[(r0 + 3) * 17 + k4];
            float4 q4v = q4p[(r0 + 4) * 17 + k4];
            float4 c0v = k4p[(c0 + 0) * 17 + k4];
            float4 c1v = k4p[(c0 + 1) * 17 + k4];
            float4 c2v = k4p[(c0 + 2) * 17 + k4];
            DOT4(s00, q0, c0v)  DOT4(s01, q0, c1v)  DOT4(s02, q0, c2v)
            DOT4(s10, q1, c0v)  DOT4(s11, q1, c1v)  DOT4(s12, q1, c2v)
            DOT4(s20, q2, c0v)  DOT4(s21, q2, c1v)  DOT4(s22, q2, c2v)
            DOT4(s30, q3, c0v)  DOT4(s31, q3, c1v)  DOT4(s32, q3, c2v)
            DOT4(s40, q4v, c0v) DOT4(s41, q4v, c1v) DOT4(s42, q4v, c2v)
        }
        // SA is 80x80: rows 76..79 / written-from-pad values are harmless
        SA[(r0 + 0) * 80 + c0 + 0] = s00; SA[(r0 + 0) * 80 + c0 + 1] = s01; SA[(r0 + 0) * 80 + c0 + 2] = s02;
        SA[(r0 + 1) * 80 + c0 + 0] = s10; SA[(r0 + 1) * 80 + c0 + 1] = s11; SA[(r0 + 1) * 80 + c0 + 2] = s12;
        SA[(r0 + 2) * 80 + c0 + 0] = s20; SA[(r0 + 2) * 80 + c0 + 1] = s21; SA[(r0 + 2) * 80 + c0 + 2] = s22;
        SA[(r0 + 3) * 80 + c0 + 0] = s30; SA[(r0 + 3) * 80 + c0 + 1] = s31; SA[(r0 + 3) * 80 + c0 + 2] = s32;
        SA[(r0 + 4) * 80 + c0 + 0] = s40; SA[(r0 + 4) * 80 + c0 + 1] = s41; SA[(r0 + 4) * 80 + c0 + 2] = s42;
    }
    __syncthreads();

    // ---- alpha per edge (gather from dense S)
    for (int t = tid; t < N_EDGES; t += 512) {
        int s = srcs[t], d = dsts[t];
        alpha[t] = 0.125f * (SA[d * 80 + s] + ewc[t] * qWe[d]);
    }
    __syncthreads();

    // ---- S dead: zero SA so it can accumulate A
    for (int t = tid; t < 6400; t += 512) SA[t] = 0.f;
    __syncthreads();

    // ---- per-node owner: max -> exp/den/csum -> A scatter (race-free)
    if (tid < N_NODES) {
        int e0 = rp_s[tid], e1 = rp_s[tid + 1];
        float m = -1e30f;
        for (int e = e0; e < e1; ++e) m = fmaxf(m, alpha[e]);
        float s = 0.f, cs = 0.f;
        for (int e = e0; e < e1; ++e) {
            float ex = expf(alpha[e] - m);
            alpha[e] = ex;
            s += ex; cs += ex * ewc[e];
        }
        float rden = 1.f / (s + 1e-16f);
        csum_s[tid] = cs * rden;
        float* Ar = SA + tid * 80;
        for (int e = e0; e < e1; ++e) Ar[srcs[e]] += alpha[e] * rden;
    }
    __syncthreads();

    // ---- dense agg = A V: 3 rows x 4 cols per thread, NAMED f4 accumulators
    {
        const int rowg = tid >> 4, colg = tid & 15;
        int n0 = rowg * 3; if (n0 > 76) n0 = 76;     // duplicates benign
        float4 g0 = {0.f, 0.f, 0.f, 0.f};
        float4 g1 = {0.f, 0.f, 0.f, 0.f};
        float4 g2 = {0.f, 0.f, 0.f, 0.f};
        const float4* A4  = (const float4*)SA;
        const float4* v4p = (const float4*)vss;

#define AGGSTEP(COMP, SS) { \
        float4 vv = v4p[(s4 * 4 + SS) * 17 + colg]; \
        g0.x += a0.COMP * vv.x; g0.y += a0.COMP * vv.y; g0.z += a0.COMP * vv.z; g0.w += a0.COMP * vv.w; \
        g1.x += a1.COMP * vv.x; g1.y += a1.COMP * vv.y; g1.z += a1.COMP * vv.z; g1.w += a1.COMP * vv.w; \
        g2.x += a2.COMP * vv.x; g2.y += a2.COMP * vv.y; g2.z += a2.COMP * vv.z; g2.w += a2.COMP * vv.w; }

        for (int s4 = 0; s4 < 20; ++s4) {
            float4 a0 = A4[(n0 + 0) * 20 + s4];
            float4 a1 = A4[(n0 + 1) * 20 + s4];
            float4 a2 = A4[(n0 + 2) * 20 + s4];
            AGGSTEP(x, 0)
            AGGSTEP(y, 1)
            AGGSTEP(z, 2)
            AGGSTEP(w, 3)
        }
#undef AGGSTEP

        const float4* o4 = (const float4*)o1s;
        const float4* e4 = (const float4*)eW;
        float4 ev = e4[colg];

#define AGGOUT(GI, I) { int n = n0 + I; if (n < N_NODES) { \
        float4 sk = o4[n * 17 + colg]; float cs = csum_s[n]; float4 r; \
        r.x = fmaxf(sk.x + GI.x + cs * ev.x, 0.f); \
        r.y = fmaxf(sk.y + GI.y + cs * ev.y, 0.f); \
        r.z = fmaxf(sk.z + GI.z + cs * ev.z, 0.f); \
        r.w = fmaxf(sk.w + GI.w + cs * ev.w, 0.f); \
        ((float4*)out1_ws)[((size_t)b * N_NODES + n) * 16 + colg] = r; } }

        AGGOUT(g0, 0)
        AGGOUT(g1, 1)
        AGGOUT(g2, 2)
#undef AGGOUT
    }
}

// ---------------------------------------------------------------------------
// K23: fused MLP. 16 rows/block, 1264 blocks, thread = 4 rows x 4 cols.
// Accumulators/operands are NAMED float4s; kk-dim expanded via component
// macros — zero address-taken vector accesses (round-5 scratch bug).
// ---------------------------------------------------------------------------
__global__ __launch_bounds__(256, 4) void k23_mlp(
    const float* __restrict__ state, const float* __restrict__ pos,
    const float* __restrict__ out1_ws, const float* __restrict__ ta_ws,
    const float* __restrict__ W1t, const float* __restrict__ b1,
    const float* __restrict__ g1, const float* __restrict__ be1,
    const float* __restrict__ W2t, const float* __restrict__ b2,
    const float* __restrict__ g2, const float* __restrict__ be2,
    const float* __restrict__ W3, const float* __restrict__ b3,
    float* __restrict__ conc_ws)
{
    __shared__ __align__(16) float A1[16 * K1PAD];   // [r][k] 7 KB
    __shared__ __align__(16) float A2[16 * 256];     // [r][k] 16 KB
    __shared__ __align__(16) float Ws[16 * 256];     // [kloc][c] 16 KB

    const int tid = threadIdx.x;
    const int lane = tid & 63;          // col group: cols 4*lane..+3
    const int wv = tid >> 6;            // wave: rows 4*wv..+3
    const int m0 = blockIdx.x * 16;

    const float4* W1t4 = (const float4*)W1t;
    const float4* W2t4 = (const float4*)W2t;
    const float4* A1r4 = (const float4*)A1;
    const float4* A2r4 = (const float4*)A2;
    float4* Ws4 = (float4*)Ws;
    const float4* Wsc4 = (const float4*)Ws;

    // ---- stage A1 [16][112]
    for (int t = tid; t < 16 * K1PAD; t += 256) {
        int r = t / K1PAD, k = t - r * K1PAD;
        int m = m0 + r;
        float v = 0.f;
        if (k < 64)       v = out1_ws[m * 64 + k];
        else if (k == 64) v = ta_ws[m / N_NODES];
        else if (k < 91)  v = state[m * RAW_FEAT + (k - 65)];
        else if (k < 97)  { int n = m - (m / N_NODES) * N_NODES;
                            v = pos[n * 6 + (k - 91)]; }
        A1[t] = v;
    }

    float4 pre0 = W1t4[(wv + 0) * 64 + lane];
    float4 pre1 = W1t4[(wv + 4) * 64 + lane];
    float4 pre2 = W1t4[(wv + 8) * 64 + lane];
    float4 pre3 = W1t4[(wv + 12) * 64 + lane];
    __syncthreads();

    float4 acc0 = {0.f, 0.f, 0.f, 0.f};
    float4 acc1 = {0.f, 0.f, 0.f, 0.f};
    float4 acc2 = {0.f, 0.f, 0.f, 0.f};
    float4 acc3 = {0.f, 0.f, 0.f, 0.f};

#define GSTEP(COMP, WIDX) { \
    float4 w = Wsc4[(kq * 4 + WIDX) * 64 + lane]; \
    acc0.x += a0.COMP * w.x; acc0.y += a0.COMP * w.y; acc0.z += a0.COMP * w.z; acc0.w += a0.COMP * w.w; \
    acc1.x += a1.COMP * w.x; acc1.y += a1.COMP * w.y; acc1.z += a1.COMP * w.z; acc1.w += a1.COMP * w.w; \
    acc2.x += a2.COMP * w.x; acc2.y += a2.COMP * w.y; acc2.z += a2.COMP * w.z; acc2.w += a2.COMP * w.w; \
    acc3.x += a3.COMP * w.x; acc3.y += a3.COMP * w.y; acc3.z += a3.COMP * w.z; acc3.w += a3.COMP * w.w; }

    // ---- GEMM1: 7 chunks of K=16
    for (int ch = 0; ch < 7; ++ch) {
        Ws4[(wv + 0) * 64 + lane] = pre0;
        Ws4[(wv + 4) * 64 + lane] = pre1;
        Ws4[(wv + 8) * 64 + lane] = pre2;
        Ws4[(wv + 12) * 64 + lane] = pre3;
        __syncthreads();
        if (ch < 6) {
            pre0 = W1t4[((ch + 1) * 16 + wv + 0) * 64 + lane];
            pre1 = W1t4[((ch + 1) * 16 + wv + 4) * 64 + lane];
            pre2 = W1t4[((ch + 1) * 16 + wv + 8) * 64 + lane];
            pre3 = W1t4[((ch + 1) * 16 + wv + 12) * 64 + lane];
        }
        #pragma unroll
        for (int kq = 0; kq < 4; ++kq) {
            float4 a0 = A1r4[(4 * wv + 0) * 28 + ch * 4 + kq];
            float4 a1 = A1r4[(4 * wv + 1) * 28 + ch * 4 + kq];
            float4 a2 = A1r4[(4 * wv + 2) * 28 + ch * 4 + kq];
            float4 a3 = A1r4[(4 * wv + 3) * 28 + ch * 4 + kq];
            GSTEP(x, 0)
            GSTEP(y, 1)
            GSTEP(z, 2)
            GSTEP(w, 3)
        }
        __syncthreads();
    }

    // prefetch W2 chunk 0 (hide under LN1)
    pre0 = W2t4[(wv + 0) * 64 + lane];
    pre1 = W2t4[(wv + 4) * 64 + lane];
    pre2 = W2t4[(wv + 8) * 64 + lane];
    pre3 = W2t4[(wv + 12) * 64 + lane];

    // ---- bias + LN1 + leaky -> A2
    {
        float4 bv = ((const float4*)b1)[lane];
        float4 gv = ((const float4*)g1)[lane];
        float4 ev = ((const float4*)be1)[lane];

#define LN1_ROW(ACC, RR) { \
        float v0 = ACC.x + bv.x, v1 = ACC.y + bv.y, v2 = ACC.z + bv.z, v3 = ACC.w + bv.w; \
        float sm = v0 + v1 + v2 + v3, sq = v0 * v0 + v1 * v1 + v2 * v2 + v3 * v3; \
        for (int off = 32; off >= 1; off >>= 1) { sm += __shfl_xor(sm, off, 64); sq += __shfl_xor(sq, off, 64); } \
        float mu = sm * (1.f / 256.f), rstd = rsqrtf(sq * (1.f / 256.f) - mu * mu + 1e-5f); \
        float4 yv; \
        yv.x = (v0 - mu) * rstd * gv.x + ev.x; yv.y = (v1 - mu) * rstd * gv.y + ev.y; \
        yv.z = (v2 - mu) * rstd * gv.z + ev.z; yv.w = (v3 - mu) * rstd * gv.w + ev.w; \
        yv.x = yv.x > 0.f ? yv.x : 0.01f * yv.x; yv.y = yv.y > 0.f ? yv.y : 0.01f * yv.y; \
        yv.z = yv.z > 0.f ? yv.z : 0.01f * yv.z; yv.w = yv.w > 0.f ? yv.w : 0.01f * yv.w; \
        ((float4*)A2)[(4 * wv + RR) * 64 + lane] = yv; }

        LN1_ROW(acc0, 0)
        LN1_ROW(acc1, 1)
        LN1_ROW(acc2, 2)
        LN1_ROW(acc3, 3)
#undef LN1_ROW
        acc0 = {0.f, 0.f, 0.f, 0.f};
        acc1 = {0.f, 0.f, 0.f, 0.f};
        acc2 = {0.f, 0.f, 0.f, 0.f};
        acc3 = {0.f, 0.f, 0.f, 0.f};
    }
    __syncthreads();

    // ---- GEMM2: 16 chunks of K=16
    for (int ch = 0; ch < 16; ++ch) {
        Ws4[(wv + 0) * 64 + lane] = pre0;
        Ws4[(wv + 4) * 64 + lane] = pre1;
        Ws4[(wv + 8) * 64 + lane] = pre2;
        Ws4[(wv + 12) * 64 + lane] = pre3;
        __syncthreads();
        if (ch < 15) {
            pre0 = W2t4[((ch + 1) * 16 + wv + 0) * 64 + lane];
            pre1 = W2t4[((ch + 1) * 16 + wv + 4) * 64 + lane];
            pre2 = W2t4[((ch + 1) * 16 + wv + 8) * 64 + lane];
            pre3 = W2t4[((ch + 1) * 16 + wv + 12) * 64 + lane];
        }
        #pragma unroll
        for (int kq = 0; kq < 4; ++kq) {
            float4 a0 = A2r4[(4 * wv + 0) * 64 + ch * 4 + kq];
            float4 a1 = A2r4[(4 * wv + 1) * 64 + ch * 4 + kq];
            float4 a2 = A2r4[(4 * wv + 2) * 64 + ch * 4 + kq];
            float4 a3 = A2r4[(4 * wv + 3) * 64 + ch * 4 + kq];
            GSTEP(x, 0)
            GSTEP(y, 1)
            GSTEP(z, 2)
            GSTEP(w, 3)
        }
        __syncthreads();
    }
#undef GSTEP

    // ---- bias + LN2 + leaky + W3 dot + softplus
    {
        float4 bv = ((const float4*)b2)[lane];
        float4 gv = ((const float4*)g2)[lane];
        float4 ev = ((const float4*)be2)[lane];
        float4 w3 = ((const float4*)W3)[lane];
        float bb3 = b3[0];

#define LN2_ROW(ACC, RR) { \
        float v0 = ACC.x + bv.x, v1 = ACC.y + bv.y, v2 = ACC.z + bv.z, v3 = ACC.w + bv.w; \
        float sm = v0 + v1 + v2 + v3, sq = v0 * v0 + v1 * v1 + v2 * v2 + v3 * v3; \
        for (int off = 32; off >= 1; off >>= 1) { sm += __shfl_xor(sm, off, 64); sq += __shfl_xor(sq, off, 64); } \
        float mu = sm * (1.f / 256.f), rstd = rsqrtf(sq * (1.f / 256.f) - mu * mu + 1e-5f); \
        float z0 = (v0 - mu) * rstd * gv.x + ev.x, z1 = (v1 - mu) * rstd * gv.y + ev.y; \
        float z2 = (v2 - mu) * rstd * gv.z + ev.z, z3 = (v3 - mu) * rstd * gv.w + ev.w; \
        z0 = z0 > 0.f ? z0 : 0.01f * z0; z1 = z1 > 0.f ? z1 : 0.01f * z1; \
        z2 = z2 > 0.f ? z2 : 0.01f * z2; z3 = z3 > 0.f ? z3 : 0.01f * z3; \
        float part = z0 * w3.x + z1 * w3.y + z2 * w3.z + z3 * w3.w; \
        for (int off = 32; off >= 1; off >>= 1) part += __shfl_xor(part, off, 64); \
        if (lane == 0) { float x = part + bb3; \
            conc_ws[m0 + 4 * wv + RR] = fmaxf(x, 0.f) + log1pf(expf(-fabsf(x))); } }

        LN2_ROW(acc0, 0)
        LN2_ROW(acc1, 1)
        LN2_ROW(acc2, 2)
        LN2_ROW(acc3, 3)
#undef LN2_ROW
    }
}

// ---------------------------------------------------------------------------
// K4: action = conc / (sum_n conc + 1e-20), per batch
// ---------------------------------------------------------------------------
__global__ __launch_bounds__(128) void k4_norm(
    const float* __restrict__ conc_ws, float* __restrict__ out)
{
    __shared__ float red[128];
    const int b = blockIdx.x, tid = threadIdx.x;
    float v = 0.f;
    if (tid < N_NODES) v = conc_ws[b * N_NODES + tid];
    red[tid] = v;
    __syncthreads();
    for (int off = 64; off >= 1; off >>= 1) {
        if (tid < off) red[tid] += red[tid + off];
        __syncthreads();
    }
    float s = red[0];
    if (tid < N_NODES) out[b * N_NODES + tid] = v / (s + 1e-20f);
}

extern "C" void kernel_launch(void* const* d_in, const int* in_sizes, int n_in,
                              void* d_out, int out_size, void* d_ws, size_t ws_size,
                              hipStream_t stream) {
    const float* state = (const float*)d_in[0];
    const float* pos   = (const float*)d_in[1];
    const float* ew    = (const float*)d_in[2];
    const float* Wq  = (const float*)d_in[3];  const float* bq  = (const float*)d_in[4];
    const float* Wk  = (const float*)d_in[5];  const float* bk  = (const float*)d_in[6];
    const float* Wv  = (const float*)d_in[7];  const float* bv  = (const float*)d_in[8];
    const float* We  = (const float*)d_in[9];
    const float* Wsk = (const float*)d_in[10]; const float* bsk = (const float*)d_in[11];
    const float* W1  = (const float*)d_in[12]; const float* b1  = (const float*)d_in[13];
    const float* g1  = (const float*)d_in[14]; const float* be1 = (const float*)d_in[15];
    const float* W2  = (const float*)d_in[16]; const float* b2  = (const float*)d_in[17];
    const float* g2  = (const float*)d_in[18]; const float* be2 = (const float*)d_in[19];
    const float* W3  = (const float*)d_in[20]; const float* b3  = (const float*)d_in[21];
    const int*   ei  = (const int*)d_in[22];

    float* ws   = (float*)d_ws;
    float* ta   = ws;                                  // 256
    float* out1 = ws + 256;                            // M*64
    float* conc = out1 + (size_t)M_ROWS * 64;          // M
    float* W1t  = conc + M_ROWS;                       // 112*256
    float* W2t  = W1t + K1PAD * HIDDEN;                // 256*256
    int*   rp   = (int*)(W2t + HIDDEN * HIDDEN);       // 80
    int*   csrc = rp + 80;                             // 3000
    int*   cdst = csrc + N_EDGES;                      // 3000
    float* cew  = (float*)(cdst + N_EDGES);            // 3000
    float* out  = (float*)d_out;

    k_prep<<<dim3(25), dim3(256), 0, stream>>>(
        W1, W2, ei, ew, W1t, W2t, rp, csrc, cdst, cew);
    k1_conv<<<dim3(BATCH), dim3(512), 0, stream>>>(
        state, pos, rp, csrc, cdst, cew,
        Wq, bq, Wk, bk, Wv, bv, We, Wsk, bsk, out1, ta);
    k23_mlp<<<dim3(M_ROWS / 16), dim3(256), 0, stream>>>(
        state, pos, out1, ta, W1t, b1, g1, be1,
        W2t, b2, g2, be2, W3, b3, conc);
    k4_norm<<<dim3(BATCH), dim3(128), 0, stream>>>(conc, out);
}

// Round 7
// 235.491 us; speedup vs baseline: 1.6824x; 1.0468x over previous
//
#include <hip/hip_runtime.h>
#include <hip/hip_bf16.h>

#define N_NODES 79
#define RAW_FEAT 26
#define D_IN 32
#define D_OUT 64
#define HIDDEN 256
#define N_EDGES 3000
#define BATCH 256
#define M_ROWS (BATCH * N_NODES)   // 20224
#define K1PAD 112                  // GEMM1 K padded to 7 chunks of 16

// ---------------------------------------------------------------------------
// k_prep: bid 0-7: W1 [256][97] -> W1t [112][256];  bid 8-23: W2 -> W2t;
//         bid 24: CSR by dst;  bid 25: Wall_t [32][256] = [Wq;Wk;Wv;Wsk]^T
//         (k-major) + ball [256] = [bq|bk|bv|bsk].
// ---------------------------------------------------------------------------
__global__ __launch_bounds__(256) void k_prep(
    const float* __restrict__ W1, const float* __restrict__ W2,
    const int* __restrict__ ei, const float* __restrict__ ew,
    const float* __restrict__ Wq, const float* __restrict__ Wk,
    const float* __restrict__ Wv, const float* __restrict__ Wsk,
    const float* __restrict__ bq, const float* __restrict__ bk,
    const float* __restrict__ bv, const float* __restrict__ bsk,
    float* __restrict__ W1t, float* __restrict__ W2t,
    float* __restrict__ Wall_t, float* __restrict__ ball,
    int* __restrict__ rp, int* __restrict__ csr_src,
    int* __restrict__ csr_dst, float* __restrict__ csr_ew)
{
    __shared__ float tile[64][65];
    __shared__ int cnt[N_NODES];
    __shared__ int base[N_NODES + 1];
    const int tid = threadIdx.x, bid = blockIdx.x;

    if (bid < 24) {
        const float* in; float* out; int C, Kpad, kb, rb;
        if (bid < 8) { in = W1; out = W1t; C = 97; Kpad = K1PAD;
                       kb = (bid & 1) * 64; rb = (bid >> 1) * 64; }
        else         { int b = bid - 8; in = W2; out = W2t; C = 256; Kpad = 256;
                       kb = (b & 3) * 64; rb = (b >> 2) * 64; }
        for (int i = tid; i < 4096; i += 256) {
            int rr = i >> 6, kk = i & 63;
            int r = rb + rr, k = kb + kk;
            tile[rr][kk] = (k < C) ? in[r * C + k] : 0.f;
        }
        __syncthreads();
        for (int i = tid; i < 4096; i += 256) {
            int kk = i >> 6, rr = i & 63;
            int k = kb + kk, r = rb + rr;
            if (k < Kpad) out[(size_t)k * HIDDEN + r] = tile[rr][kk];
        }
        return;
    }

    if (bid == 25) {
        for (int t = tid; t < 32 * 256; t += 256) {
            int k = t >> 8, j = t & 255;
            float v;
            if (j < 64)       v = Wq [j * 32 + k];
            else if (j < 128) v = Wk [(j - 64) * 32 + k];
            else if (j < 192) v = Wv [(j - 128) * 32 + k];
            else              v = Wsk[(j - 192) * 32 + k];
            Wall_t[t] = v;
        }
        if (tid < 64) {
            ball[tid]       = bq[tid];
            ball[64 + tid]  = bk[tid];
            ball[128 + tid] = bv[tid];
            ball[192 + tid] = bsk[tid];
        }
        return;
    }

    // ---- CSR build (bid 24)
    if (tid < N_NODES) cnt[tid] = 0;
    __syncthreads();
    for (int e = tid; e < N_EDGES; e += 256) atomicAdd(&cnt[ei[N_EDGES + e]], 1);
    __syncthreads();
    if (tid == 0) {
        int run = 0;
        for (int n = 0; n < N_NODES; ++n) { base[n] = run; run += cnt[n]; }
        base[N_NODES] = run;
    }
    __syncthreads();
    if (tid < N_NODES + 1) rp[tid] = base[tid];
    if (tid < N_NODES) cnt[tid] = base[tid];
    __syncthreads();
    for (int e = tid; e < N_EDGES; e += 256) {
        int d = ei[N_EDGES + e];
        int p = atomicAdd(&cnt[d], 1);
        csr_src[p] = ei[e];
        csr_dst[p] = d;
        csr_ew[p]  = ew[e];
    }
}

#define DOT4(S, Aa, Bb) S += Aa.x * Bb.x + Aa.y * Bb.y + Aa.z * Bb.z + Aa.w * Bb.w;

// ---------------------------------------------------------------------------
// K_QKV: dense GEMM over all rows: [q|k|v|skip] = X @ Wall^T + ball.
// 632 blocks x 32 rows; thread = 4 rows x (4+4) cols (c and c+128).
// ---------------------------------------------------------------------------
__global__ __launch_bounds__(256) void k_qkv(
    const float* __restrict__ state, const float* __restrict__ pos,
    const float* __restrict__ Wall_t, const float* __restrict__ ball,
    float* __restrict__ qkvs)
{
    __shared__ __align__(16) float Ax[32 * 32];     // 4 KB
    __shared__ __align__(16) float Ws[32 * 256];    // 32 KB

    const int tid = threadIdx.x;
    const int cg = tid & 31;            // cols cg*4..+3 and 128+cg*4..+3
    const int rg = tid >> 5;            // rows rg*4..+3
    const int m0 = blockIdx.x * 32;

    for (int t = tid; t < 32 * 32; t += 256) {
        int r = t >> 5, k = t & 31;
        int m = m0 + r, n = m - (m / N_NODES) * N_NODES;
        Ax[t] = (k < RAW_FEAT) ? state[m * RAW_FEAT + k] : pos[n * 6 + (k - RAW_FEAT)];
    }
    {
        const float4* Wg4 = (const float4*)Wall_t;
        float4* Ws4w = (float4*)Ws;
        #pragma unroll
        for (int i = 0; i < 8; ++i) Ws4w[tid + 256 * i] = Wg4[tid + 256 * i];
    }
    __syncthreads();

    float4 accL0 = {0,0,0,0}, accL1 = {0,0,0,0}, accL2 = {0,0,0,0}, accL3 = {0,0,0,0};
    float4 accH0 = {0,0,0,0}, accH1 = {0,0,0,0}, accH2 = {0,0,0,0}, accH3 = {0,0,0,0};
    const float4* Ax4 = (const float4*)Ax;
    const float4* Ws4 = (const float4*)Ws;

#define QSTEP(COMP, KS) { \
    float4 wL = Ws4[(kq * 4 + KS) * 64 + cg]; \
    float4 wH = Ws4[(kq * 4 + KS) * 64 + 32 + cg]; \
    accL0.x += a0.COMP * wL.x; accL0.y += a0.COMP * wL.y; accL0.z += a0.COMP * wL.z; accL0.w += a0.COMP * wL.w; \
    accL1.x += a1.COMP * wL.x; accL1.y += a1.COMP * wL.y; accL1.z += a1.COMP * wL.z; accL1.w += a1.COMP * wL.w; \
    accL2.x += a2.COMP * wL.x; accL2.y += a2.COMP * wL.y; accL2.z += a2.COMP * wL.z; accL2.w += a2.COMP * wL.w; \
    accL3.x += a3.COMP * wL.x; accL3.y += a3.COMP * wL.y; accL3.z += a3.COMP * wL.z; accL3.w += a3.COMP * wL.w; \
    accH0.x += a0.COMP * wH.x; accH0.y += a0.COMP * wH.y; accH0.z += a0.COMP * wH.z; accH0.w += a0.COMP * wH.w; \
    accH1.x += a1.COMP * wH.x; accH1.y += a1.COMP * wH.y; accH1.z += a1.COMP * wH.z; accH1.w += a1.COMP * wH.w; \
    accH2.x += a2.COMP * wH.x; accH2.y += a2.COMP * wH.y; accH2.z += a2.COMP * wH.z; accH2.w += a2.COMP * wH.w; \
    accH3.x += a3.COMP * wH.x; accH3.y += a3.COMP * wH.y; accH3.z += a3.COMP * wH.z; accH3.w += a3.COMP * wH.w; }

    #pragma unroll
    for (int kq = 0; kq < 8; ++kq) {
        float4 a0 = Ax4[(rg * 4 + 0) * 8 + kq];
        float4 a1 = Ax4[(rg * 4 + 1) * 8 + kq];
        float4 a2 = Ax4[(rg * 4 + 2) * 8 + kq];
        float4 a3 = Ax4[(rg * 4 + 3) * 8 + kq];
        QSTEP(x, 0)
        QSTEP(y, 1)
        QSTEP(z, 2)
        QSTEP(w, 3)
    }
#undef QSTEP

    {
        float4 bL = ((const float4*)ball)[cg];
        float4 bH = ((const float4*)ball)[32 + cg];
        float4* o4 = (float4*)qkvs;
#define QOUT(ACCL, ACCH, RR) { \
        float4 vL, vH; \
        vL.x = ACCL.x + bL.x; vL.y = ACCL.y + bL.y; vL.z = ACCL.z + bL.z; vL.w = ACCL.w + bL.w; \
        vH.x = ACCH.x + bH.x; vH.y = ACCH.y + bH.y; vH.z = ACCH.z + bH.z; vH.w = ACCH.w + bH.w; \
        o4[(size_t)(m0 + rg * 4 + RR) * 64 + cg] = vL; \
        o4[(size_t)(m0 + rg * 4 + RR) * 64 + 32 + cg] = vH; }
        QOUT(accL0, accH0, 0)
        QOUT(accL1, accH1, 1)
        QOUT(accL2, accH2, 2)
        QOUT(accL3, accH3, 3)
#undef QOUT
    }
}

// ---------------------------------------------------------------------------
// K1: per-batch attention. q/k/v/skip staged from qkvs (coalesced);
// S = QK^T, alpha gather, per-node owner softmax scans, A scatter, agg = A V.
// ---------------------------------------------------------------------------
__global__ __launch_bounds__(512) void k1_conv(
    const float* __restrict__ state, const float* __restrict__ qkvs,
    const int* __restrict__ rp_g, const int* __restrict__ csrc_g,
    const int* __restrict__ cdst_g, const float* __restrict__ cew_g,
    const float* __restrict__ We,
    float* __restrict__ out1_ws, float* __restrict__ ta_ws)
{
    __shared__ __align__(16) float qs [80 * 68];   // row 79 zero pad
    __shared__ __align__(16) float kss[80 * 68];
    __shared__ __align__(16) float vss[80 * 68];
    __shared__ __align__(16) float o1s[N_NODES * 68];
    __shared__ __align__(16) float SA[80 * 80];    // S then (zeroed) A
    __shared__ __align__(16) float alpha[N_EDGES];
    __shared__ __align__(16) float ewc[N_EDGES];
    __shared__ unsigned short srcs[N_EDGES], dsts[N_EDGES];
    __shared__ __align__(16) float eW[64];
    __shared__ int   rp_s[80];
    __shared__ float qWe[80], csum_s[80];
    __shared__ float red80[80];

    const int b = blockIdx.x, tid = threadIdx.x;

    // ---- stage q/k/v/skip rows from qkvs (f4, coalesced)
    {
        const float4* qk4 = (const float4*)qkvs;
        for (int t = tid; t < N_NODES * 64; t += 512) {
            int n = t >> 6, j = t & 63;
            float4 v = qk4[(size_t)(b * N_NODES + n) * 64 + j];
            if (j < 16)      ((float4*)qs )[n * 17 + j]        = v;
            else if (j < 32) ((float4*)kss)[n * 17 + (j - 16)] = v;
            else if (j < 48) ((float4*)vss)[n * 17 + (j - 32)] = v;
            else             ((float4*)o1s)[n * 17 + (j - 48)] = v;
        }
    }
    for (int t = tid; t < N_EDGES; t += 512) {
        srcs[t] = (unsigned short)csrc_g[t];
        dsts[t] = (unsigned short)cdst_g[t];
        ewc[t]  = cew_g[t];
    }
    if (tid < 64) eW[tid] = We[tid];
    if (tid < 80) rp_s[tid] = rp_g[tid];
    if (tid < 79) red80[tid] = state[(b * N_NODES + tid) * RAW_FEAT + 1];
    if (tid == 79) red80[79] = 0.f;
    for (int t = tid; t < 68; t += 512) {          // zero pad row 79
        qs[79 * 68 + t] = 0.f; kss[79 * 68 + t] = 0.f; vss[79 * 68 + t] = 0.f;
    }
    __syncthreads();

    // ---- ta = sum_n x[n,1]
    for (int off = 64; off >= 1; off >>= 1) {
        if (tid < off && tid + off < 80) red80[tid] += red80[tid + off];
        __syncthreads();
    }
    if (tid == 0) ta_ws[b] = red80[0];

    // ---- qWe[n] = dot(q[n], We)
    if (tid < N_NODES) {
        const float4* q4 = (const float4*)(qs + tid * 68);
        const float4* e4 = (const float4*)eW;
        float s = 0.f;
        #pragma unroll
        for (int i = 0; i < 16; ++i) {
            float4 a = q4[i], e = e4[i];
            DOT4(s, a, e)
        }
        qWe[tid] = s;
    }
    __syncthreads();

    // ---- dense S = Q K^T: 5 rows x 3 cols per thread, named accumulators
    {
        const int rg = tid >> 5, cgp = tid & 31;
        const int r0 = rg * 5;
        int c0 = cgp * 3; if (c0 > 76) c0 = 76;
        float s00 = 0, s01 = 0, s02 = 0;
        float s10 = 0, s11 = 0, s12 = 0;
        float s20 = 0, s21 = 0, s22 = 0;
        float s30 = 0, s31 = 0, s32 = 0;
        float s40 = 0, s41 = 0, s42 = 0;
        const float4* q4p = (const float4*)qs;
        const float4* k4p = (const float4*)kss;
        for (int k4 = 0; k4 < 16; ++k4) {
            float4 q0 = q4p[(r0 + 0) * 17 + k4];
            float4 q1 = q4p[(r0 + 1) * 17 + k4];
            float4 q2 = q4p[(r0 + 2) * 17 + k4];
            float4 q3 = q4p[(r0 + 3) * 17 + k4];
            float4 q4v = q4p[(r0 + 4) * 17 + k4];
            float4 c0v = k4p[(c0 + 0) * 17 + k4];
            float4 c1v = k4p[(c0 + 1) * 17 + k4];
            float4 c2v = k4p[(c0 + 2) * 17 + k4];
            DOT4(s00, q0, c0v)  DOT4(s01, q0, c1v)  DOT4(s02, q0, c2v)
            DOT4(s10, q1, c0v)  DOT4(s11, q1, c1v)  DOT4(s12, q1, c2v)
            DOT4(s20, q2, c0v)  DOT4(s21, q2, c1v)  DOT4(s22, q2, c2v)
            DOT4(s30, q3, c0v)  DOT4(s31, q3, c1v)  DOT4(s32, q3, c2v)
            DOT4(s40, q4v, c0v) DOT4(s41, q4v, c1v) DOT4(s42, q4v, c2v)
        }
        SA[(r0 + 0) * 80 + c0 + 0] = s00; SA[(r0 + 0) * 80 + c0 + 1] = s01; SA[(r0 + 0) * 80 + c0 + 2] = s02;
        SA[(r0 + 1) * 80 + c0 + 0] = s10; SA[(r0 + 1) * 80 + c0 + 1] = s11; SA[(r0 + 1) * 80 + c0 + 2] = s12;
        SA[(r0 + 2) * 80 + c0 + 0] = s20; SA[(r0 + 2) * 80 + c0 + 1] = s21; SA[(r0 + 2) * 80 + c0 + 2] = s22;
        SA[(r0 + 3) * 80 + c0 + 0] = s30; SA[(r0 + 3) * 80 + c0 + 1] = s31; SA[(r0 + 3) * 80 + c0 + 2] = s32;
        SA[(r0 + 4) * 80 + c0 + 0] = s40; SA[(r0 + 4) * 80 + c0 + 1] = s41; SA[(r0 + 4) * 80 + c0 + 2] = s42;
    }
    __syncthreads();

    // ---- alpha per edge
    for (int t = tid; t < N_EDGES; t += 512) {
        int s = srcs[t], d = dsts[t];
        alpha[t] = 0.125f * (SA[d * 80 + s] + ewc[t] * qWe[d]);
    }
    __syncthreads();

    // ---- zero SA for A accumulation
    for (int t = tid; t < 6400; t += 512) SA[t] = 0.f;
    __syncthreads();

    // ---- per-node owner: max -> exp/den/csum -> A scatter
    if (tid < N_NODES) {
        int e0 = rp_s[tid], e1 = rp_s[tid + 1];
        float m = -1e30f;
        for (int e = e0; e < e1; ++e) m = fmaxf(m, alpha[e]);
        float s = 0.f, cs = 0.f;
        for (int e = e0; e < e1; ++e) {
            float ex = expf(alpha[e] - m);
            alpha[e] = ex;
            s += ex; cs += ex * ewc[e];
        }
        float rden = 1.f / (s + 1e-16f);
        csum_s[tid] = cs * rden;
        float* Ar = SA + tid * 80;
        for (int e = e0; e < e1; ++e) Ar[srcs[e]] += alpha[e] * rden;
    }
    __syncthreads();

    // ---- dense agg = A V + epilogue (named f4 accumulators)
    {
        const int rowg = tid >> 4, colg = tid & 15;
        int n0 = rowg * 3; if (n0 > 76) n0 = 76;
        float4 g0 = {0.f, 0.f, 0.f, 0.f};
        float4 g1 = {0.f, 0.f, 0.f, 0.f};
        float4 g2 = {0.f, 0.f, 0.f, 0.f};
        const float4* A4  = (const float4*)SA;
        const float4* v4p = (const float4*)vss;

#define AGGSTEP(COMP, SS) { \
        float4 vv = v4p[(s4 * 4 + SS) * 17 + colg]; \
        g0.x += a0.COMP * vv.x; g0.y += a0.COMP * vv.y; g0.z += a0.COMP * vv.z; g0.w += a0.COMP * vv.w; \
        g1.x += a1.COMP * vv.x; g1.y += a1.COMP * vv.y; g1.z += a1.COMP * vv.z; g1.w += a1.COMP * vv.w; \
        g2.x += a2.COMP * vv.x; g2.y += a2.COMP * vv.y; g2.z += a2.COMP * vv.z; g2.w += a2.COMP * vv.w; }

        for (int s4 = 0; s4 < 20; ++s4) {
            float4 a0 = A4[(n0 + 0) * 20 + s4];
            float4 a1 = A4[(n0 + 1) * 20 + s4];
            float4 a2 = A4[(n0 + 2) * 20 + s4];
            AGGSTEP(x, 0)
            AGGSTEP(y, 1)
            AGGSTEP(z, 2)
            AGGSTEP(w, 3)
        }
#undef AGGSTEP

        const float4* o4 = (const float4*)o1s;
        const float4* e4 = (const float4*)eW;
        float4 ev = e4[colg];

#define AGGOUT(GI, I) { int n = n0 + I; if (n < N_NODES) { \
        float4 sk = o4[n * 17 + colg]; float cs = csum_s[n]; float4 r; \
        r.x = fmaxf(sk.x + GI.x + cs * ev.x, 0.f); \
        r.y = fmaxf(sk.y + GI.y + cs * ev.y, 0.f); \
        r.z = fmaxf(sk.z + GI.z + cs * ev.z, 0.f); \
        r.w = fmaxf(sk.w + GI.w + cs * ev.w, 0.f); \
        ((float4*)out1_ws)[((size_t)b * N_NODES + n) * 16 + colg] = r; } }

        AGGOUT(g0, 0)
        AGGOUT(g1, 1)
        AGGOUT(g2, 2)
#undef AGGOUT
    }
}

// ---------------------------------------------------------------------------
// K23: fused MLP. 632 blocks x 32 rows; thread = 4 rows x (4+4) cols.
// W staged in 16-k-row LDS chunks with register prefetch. No min-occupancy
// bound (round-6: __launch_bounds__(256,4) forced 64 VGPR -> 82 MB spills).
// ---------------------------------------------------------------------------
__global__ __launch_bounds__(256) void k23_mlp(
    const float* __restrict__ state, const float* __restrict__ pos,
    const float* __restrict__ out1_ws, const float* __restrict__ ta_ws,
    const float* __restrict__ W1t, const float* __restrict__ b1,
    const float* __restrict__ g1, const float* __restrict__ be1,
    const float* __restrict__ W2t, const float* __restrict__ b2,
    const float* __restrict__ g2, const float* __restrict__ be2,
    const float* __restrict__ W3, const float* __restrict__ b3,
    float* __restrict__ conc_ws)
{
    __shared__ __align__(16) float A1[32 * K1PAD];   // 14.3 KB
    __shared__ __align__(16) float A2[32 * 256];     // 32 KB
    __shared__ __align__(16) float Ws[16 * 256];     // 16 KB

    const int tid = threadIdx.x;
    const int cg = tid & 31;            // cols cg*4..+3 and 128+cg*4..+3
    const int rg = tid >> 5;            // rows rg*4..+3
    const int m0 = blockIdx.x * 32;

    const float4* W1t4 = (const float4*)W1t;
    const float4* W2t4 = (const float4*)W2t;
    const float4* A1_4 = (const float4*)A1;
    const float4* A2_4 = (const float4*)A2;
    float4* Ws4w = (float4*)Ws;
    const float4* Ws4 = (const float4*)Ws;

    // ---- stage A1 [32][112]
    for (int t = tid; t < 32 * K1PAD; t += 256) {
        int r = t / K1PAD, k = t - r * K1PAD;
        int m = m0 + r;
        float v = 0.f;
        if (k < 64)       v = out1_ws[m * 64 + k];
        else if (k == 64) v = ta_ws[m / N_NODES];
        else if (k < 91)  v = state[m * RAW_FEAT + (k - 65)];
        else if (k < 97)  { int n = m - (m / N_NODES) * N_NODES;
                            v = pos[n * 6 + (k - 91)]; }
        A1[t] = v;
    }
    float4 pre0 = W1t4[tid];
    float4 pre1 = W1t4[tid + 256];
    float4 pre2 = W1t4[tid + 512];
    float4 pre3 = W1t4[tid + 768];
    __syncthreads();

    float4 accL0 = {0,0,0,0}, accL1 = {0,0,0,0}, accL2 = {0,0,0,0}, accL3 = {0,0,0,0};
    float4 accH0 = {0,0,0,0}, accH1 = {0,0,0,0}, accH2 = {0,0,0,0}, accH3 = {0,0,0,0};

#define KSTEP(COMP, KS) { \
    float4 wL = Ws4[(kq * 4 + KS) * 64 + cg]; \
    float4 wH = Ws4[(kq * 4 + KS) * 64 + 32 + cg]; \
    accL0.x += a0.COMP * wL.x; accL0.y += a0.COMP * wL.y; accL0.z += a0.COMP * wL.z; accL0.w += a0.COMP * wL.w; \
    accL1.x += a1.COMP * wL.x; accL1.y += a1.COMP * wL.y; accL1.z += a1.COMP * wL.z; accL1.w += a1.COMP * wL.w; \
    accL2.x += a2.COMP * wL.x; accL2.y += a2.COMP * wL.y; accL2.z += a2.COMP * wL.z; accL2.w += a2.COMP * wL.w; \
    accL3.x += a3.COMP * wL.x; accL3.y += a3.COMP * wL.y; accL3.z += a3.COMP * wL.z; accL3.w += a3.COMP * wL.w; \
    accH0.x += a0.COMP * wH.x; accH0.y += a0.COMP * wH.y; accH0.z += a0.COMP * wH.z; accH0.w += a0.COMP * wH.w; \
    accH1.x += a1.COMP * wH.x; accH1.y += a1.COMP * wH.y; accH1.z += a1.COMP * wH.z; accH1.w += a1.COMP * wH.w; \
    accH2.x += a2.COMP * wH.x; accH2.y += a2.COMP * wH.y; accH2.z += a2.COMP * wH.z; accH2.w += a2.COMP * wH.w; \
    accH3.x += a3.COMP * wH.x; accH3.y += a3.COMP * wH.y; accH3.z += a3.COMP * wH.z; accH3.w += a3.COMP * wH.w; }

    // ---- GEMM1: 7 chunks of K=16
    for (int ch = 0; ch < 7; ++ch) {
        Ws4w[tid] = pre0; Ws4w[tid + 256] = pre1;
        Ws4w[tid + 512] = pre2; Ws4w[tid + 768] = pre3;
        __syncthreads();
        if (ch < 6) {
            pre0 = W1t4[(ch + 1) * 1024 + tid];
            pre1 = W1t4[(ch + 1) * 1024 + tid + 256];
            pre2 = W1t4[(ch + 1) * 1024 + tid + 512];
            pre3 = W1t4[(ch + 1) * 1024 + tid + 768];
        } else {            // prefetch W2 chunk 0 (hides under LN1)
            pre0 = W2t4[tid];
            pre1 = W2t4[tid + 256];
            pre2 = W2t4[tid + 512];
            pre3 = W2t4[tid + 768];
        }
        #pragma unroll
        for (int kq = 0; kq < 4; ++kq) {
            float4 a0 = A1_4[(rg * 4 + 0) * 28 + ch * 4 + kq];
            float4 a1 = A1_4[(rg * 4 + 1) * 28 + ch * 4 + kq];
            float4 a2 = A1_4[(rg * 4 + 2) * 28 + ch * 4 + kq];
            float4 a3 = A1_4[(rg * 4 + 3) * 28 + ch * 4 + kq];
            KSTEP(x, 0)
            KSTEP(y, 1)
            KSTEP(z, 2)
            KSTEP(w, 3)
        }
        __syncthreads();
    }

    // ---- bias + LN1 + leaky -> A2
    {
        float4 bL = ((const float4*)b1)[cg],  bH = ((const float4*)b1)[32 + cg];
        float4 gL = ((const float4*)g1)[cg],  gH = ((const float4*)g1)[32 + cg];
        float4 eL = ((const float4*)be1)[cg], eH = ((const float4*)be1)[32 + cg];

#define LN1_ROW(AL, AH, RR) { \
        float v0 = AL.x + bL.x, v1 = AL.y + bL.y, v2 = AL.z + bL.z, v3 = AL.w + bL.w; \
        float v4 = AH.x + bH.x, v5 = AH.y + bH.y, v6 = AH.z + bH.z, v7 = AH.w + bH.w; \
        float sm = v0 + v1 + v2 + v3 + v4 + v5 + v6 + v7; \
        float sq = v0*v0 + v1*v1 + v2*v2 + v3*v3 + v4*v4 + v5*v5 + v6*v6 + v7*v7; \
        for (int off = 16; off >= 1; off >>= 1) { sm += __shfl_xor(sm, off, 64); sq += __shfl_xor(sq, off, 64); } \
        float mu = sm * (1.f / 256.f), rstd = rsqrtf(sq * (1.f / 256.f) - mu * mu + 1e-5f); \
        float4 yL, yH; \
        yL.x = (v0 - mu) * rstd * gL.x + eL.x; yL.y = (v1 - mu) * rstd * gL.y + eL.y; \
        yL.z = (v2 - mu) * rstd * gL.z + eL.z; yL.w = (v3 - mu) * rstd * gL.w + eL.w; \
        yH.x = (v4 - mu) * rstd * gH.x + eH.x; yH.y = (v5 - mu) * rstd * gH.y + eH.y; \
        yH.z = (v6 - mu) * rstd * gH.z + eH.z; yH.w = (v7 - mu) * rstd * gH.w + eH.w; \
        yL.x = yL.x > 0.f ? yL.x : 0.01f * yL.x; yL.y = yL.y > 0.f ? yL.y : 0.01f * yL.y; \
        yL.z = yL.z > 0.f ? yL.z : 0.01f * yL.z; yL.w = yL.w > 0.f ? yL.w : 0.01f * yL.w; \
        yH.x = yH.x > 0.f ? yH.x : 0.01f * yH.x; yH.y = yH.y > 0.f ? yH.y : 0.01f * yH.y; \
        yH.z = yH.z > 0.f ? yH.z : 0.01f * yH.z; yH.w = yH.w > 0.f ? yH.w : 0.01f * yH.w; \
        ((float4*)A2)[(rg * 4 + RR) * 64 + cg] = yL; \
        ((float4*)A2)[(rg * 4 + RR) * 64 + 32 + cg] = yH; }

        LN1_ROW(accL0, accH0, 0)
        LN1_ROW(accL1, accH1, 1)
        LN1_ROW(accL2, accH2, 2)
        LN1_ROW(accL3, accH3, 3)
#undef LN1_ROW
        accL0 = {0,0,0,0}; accL1 = {0,0,0,0}; accL2 = {0,0,0,0}; accL3 = {0,0,0,0};
        accH0 = {0,0,0,0}; accH1 = {0,0,0,0}; accH2 = {0,0,0,0}; accH3 = {0,0,0,0};
    }

    // ---- GEMM2: 16 chunks of K=16 (chunk-0 barrier also fences A2 writes)
    for (int ch = 0; ch < 16; ++ch) {
        Ws4w[tid] = pre0; Ws4w[tid + 256] = pre1;
        Ws4w[tid + 512] = pre2; Ws4w[tid + 768] = pre3;
        __syncthreads();
        if (ch < 15) {
            pre0 = W2t4[(ch + 1) * 1024 + tid];
            pre1 = W2t4[(ch + 1) * 1024 + tid + 256];
            pre2 = W2t4[(ch + 1) * 1024 + tid + 512];
            pre3 = W2t4[(ch + 1) * 1024 + tid + 768];
        }
        #pragma unroll
        for (int kq = 0; kq < 4; ++kq) {
            float4 a0 = A2_4[(rg * 4 + 0) * 64 + ch * 4 + kq];
            float4 a1 = A2_4[(rg * 4 + 1) * 64 + ch * 4 + kq];
            float4 a2 = A2_4[(rg * 4 + 2) * 64 + ch * 4 + kq];
            float4 a3 = A2_4[(rg * 4 + 3) * 64 + ch * 4 + kq];
            KSTEP(x, 0)
            KSTEP(y, 1)
            KSTEP(z, 2)
            KSTEP(w, 3)
        }
        __syncthreads();
    }
#undef KSTEP

    // ---- bias + LN2 + leaky + W3 dot + softplus
    {
        float4 bL = ((const float4*)b2)[cg],  bH = ((const float4*)b2)[32 + cg];
        float4 gL = ((const float4*)g2)[cg],  gH = ((const float4*)g2)[32 + cg];
        float4 eL = ((const float4*)be2)[cg], eH = ((const float4*)be2)[32 + cg];
        float4 wL3 = ((const float4*)W3)[cg], wH3 = ((const float4*)W3)[32 + cg];
        float bb3 = b3[0];

#define LN2_ROW(AL, AH, RR) { \
        float v0 = AL.x + bL.x, v1 = AL.y + bL.y, v2 = AL.z + bL.z, v3 = AL.w + bL.w; \
        float v4 = AH.x + bH.x, v5 = AH.y + bH.y, v6 = AH.z + bH.z, v7 = AH.w + bH.w; \
        float sm = v0 + v1 + v2 + v3 + v4 + v5 + v6 + v7; \
        float sq = v0*v0 + v1*v1 + v2*v2 + v3*v3 + v4*v4 + v5*v5 + v6*v6 + v7*v7; \
        for (int off = 16; off >= 1; off >>= 1) { sm += __shfl_xor(sm, off, 64); sq += __shfl_xor(sq, off, 64); } \
        float mu = sm * (1.f / 256.f), rstd = rsqrtf(sq * (1.f / 256.f) - mu * mu + 1e-5f); \
        float z0 = (v0 - mu) * rstd * gL.x + eL.x, z1 = (v1 - mu) * rstd * gL.y + eL.y; \
        float z2 = (v2 - mu) * rstd * gL.z + eL.z, z3 = (v3 - mu) * rstd * gL.w + eL.w; \
        float z4 = (v4 - mu) * rstd * gH.x + eH.x, z5 = (v5 - mu) * rstd * gH.y + eH.y; \
        float z6 = (v6 - mu) * rstd * gH.z + eH.z, z7 = (v7 - mu) * rstd * gH.w + eH.w; \
        z0 = z0 > 0.f ? z0 : 0.01f * z0; z1 = z1 > 0.f ? z1 : 0.01f * z1; \
        z2 = z2 > 0.f ? z2 : 0.01f * z2; z3 = z3 > 0.f ? z3 : 0.01f * z3; \
        z4 = z4 > 0.f ? z4 : 0.01f * z4; z5 = z5 > 0.f ? z5 : 0.01f * z5; \
        z6 = z6 > 0.f ? z6 : 0.01f * z6; z7 = z7 > 0.f ? z7 : 0.01f * z7; \
        float part = z0 * wL3.x + z1 * wL3.y + z2 * wL3.z + z3 * wL3.w \
                   + z4 * wH3.x + z5 * wH3.y + z6 * wH3.z + z7 * wH3.w; \
        for (int off = 16; off >= 1; off >>= 1) part += __shfl_xor(part, off, 64); \
        if (cg == 0) { float x = part + bb3; \
            conc_ws[m0 + rg * 4 + RR] = fmaxf(x, 0.f) + log1pf(expf(-fabsf(x))); } }

        LN2_ROW(accL0, accH0, 0)
        LN2_ROW(accL1, accH1, 1)
        LN2_ROW(accL2, accH2, 2)
        LN2_ROW(accL3, accH3, 3)
#undef LN2_ROW
    }
}

// ---------------------------------------------------------------------------
// K4: action = conc / (sum_n conc + 1e-20), per batch
// ---------------------------------------------------------------------------
__global__ __launch_bounds__(128) void k4_norm(
    const float* __restrict__ conc_ws, float* __restrict__ out)
{
    __shared__ float red[128];
    const int b = blockIdx.x, tid = threadIdx.x;
    float v = 0.f;
    if (tid < N_NODES) v = conc_ws[b * N_NODES + tid];
    red[tid] = v;
    __syncthreads();
    for (int off = 64; off >= 1; off >>= 1) {
        if (tid < off) red[tid] += red[tid + off];
        __syncthreads();
    }
    float s = red[0];
    if (tid < N_NODES) out[b * N_NODES + tid] = v / (s + 1e-20f);
}

extern "C" void kernel_launch(void* const* d_in, const int* in_sizes, int n_in,
                              void* d_out, int out_size, void* d_ws, size_t ws_size,
                              hipStream_t stream) {
    const float* state = (const float*)d_in[0];
    const float* pos   = (const float*)d_in[1];
    const float* ew    = (const float*)d_in[2];
    const float* Wq  = (const float*)d_in[3];  const float* bq  = (const float*)d_in[4];
    const float* Wk  = (const float*)d_in[5];  const float* bk  = (const float*)d_in[6];
    const float* Wv  = (const float*)d_in[7];  const float* bv  = (const float*)d_in[8];
    const float* We  = (const float*)d_in[9];
    const float* Wsk = (const float*)d_in[10]; const float* bsk = (const float*)d_in[11];
    const float* W1  = (const float*)d_in[12]; const float* b1  = (const float*)d_in[13];
    const float* g1  = (const float*)d_in[14]; const float* be1 = (const float*)d_in[15];
    const float* W2  = (const float*)d_in[16]; const float* b2  = (const float*)d_in[17];
    const float* g2  = (const float*)d_in[18]; const float* be2 = (const float*)d_in[19];
    const float* W3  = (const float*)d_in[20]; const float* b3  = (const float*)d_in[21];
    const int*   ei  = (const int*)d_in[22];

    float* ws    = (float*)d_ws;
    float* ta    = ws;                                  // 256
    float* out1  = ws + 256;                            // M*64
    float* conc  = out1 + (size_t)M_ROWS * 64;          // M
    float* W1t   = conc + M_ROWS;                       // 112*256
    float* W2t   = W1t + K1PAD * HIDDEN;                // 256*256
    float* Wall  = W2t + HIDDEN * HIDDEN;               // 32*256
    float* ball  = Wall + 32 * 256;                     // 256
    float* qkvs  = ball + 256;                          // M*256
    int*   rp    = (int*)(qkvs + (size_t)M_ROWS * 256); // 80
    int*   csrc  = rp + 80;                             // 3000
    int*   cdst  = csrc + N_EDGES;                      // 3000
    float* cew   = (float*)(cdst + N_EDGES);            // 3000
    float* out   = (float*)d_out;

    k_prep<<<dim3(26), dim3(256), 0, stream>>>(
        W1, W2, ei, ew, Wq, Wk, Wv, Wsk, bq, bk, bv, bsk,
        W1t, W2t, Wall, ball, rp, csrc, cdst, cew);
    k_qkv<<<dim3(M_ROWS / 32), dim3(256), 0, stream>>>(
        state, pos, Wall, ball, qkvs);
    k1_conv<<<dim3(BATCH), dim3(512), 0, stream>>>(
        state, qkvs, rp, csrc, cdst, cew, We, out1, ta);
    k23_mlp<<<dim3(M_ROWS / 32), dim3(256), 0, stream>>>(
        state, pos, out1, ta, W1t, b1, g1, be1,
        W2t, b2, g2, be2, W3, b3, conc);
    k4_norm<<<dim3(BATCH), dim3(128), 0, stream>>>(conc, out);
}

// Round 8
// 220.428 us; speedup vs baseline: 1.7973x; 1.0683x over previous
//
#include <hip/hip_runtime.h>
#include <hip/hip_bf16.h>

#define N_NODES 79
#define RAW_FEAT 26
#define D_IN 32
#define D_OUT 64
#define HIDDEN 256
#define N_EDGES 3000
#define BATCH 256
#define M_ROWS (BATCH * N_NODES)   // 20224
#define K1PAD 112                  // GEMM1 K padded to 7 chunks of 16

// ---------------------------------------------------------------------------
// k_prep: bid 0-7: W1 [256][97] -> W1t [112][256];  bid 8-23: W2 -> W2t;
//         bid 24: CSR by dst;  bid 25: Wall_t [32][256] = [Wq;Wk;Wv;Wsk]^T
//         (k-major) + ball [256] = [bq|bk|bv|bsk].
// ---------------------------------------------------------------------------
__global__ __launch_bounds__(256) void k_prep(
    const float* __restrict__ W1, const float* __restrict__ W2,
    const int* __restrict__ ei, const float* __restrict__ ew,
    const float* __restrict__ Wq, const float* __restrict__ Wk,
    const float* __restrict__ Wv, const float* __restrict__ Wsk,
    const float* __restrict__ bq, const float* __restrict__ bk,
    const float* __restrict__ bv, const float* __restrict__ bsk,
    float* __restrict__ W1t, float* __restrict__ W2t,
    float* __restrict__ Wall_t, float* __restrict__ ball,
    int* __restrict__ rp, int* __restrict__ csr_src,
    int* __restrict__ csr_dst, float* __restrict__ csr_ew)
{
    __shared__ float tile[64][65];
    __shared__ int cnt[N_NODES];
    __shared__ int base[N_NODES + 1];
    const int tid = threadIdx.x, bid = blockIdx.x;

    if (bid < 24) {
        const float* in; float* out; int C, Kpad, kb, rb;
        if (bid < 8) { in = W1; out = W1t; C = 97; Kpad = K1PAD;
                       kb = (bid & 1) * 64; rb = (bid >> 1) * 64; }
        else         { int b = bid - 8; in = W2; out = W2t; C = 256; Kpad = 256;
                       kb = (b & 3) * 64; rb = (b >> 2) * 64; }
        for (int i = tid; i < 4096; i += 256) {
            int rr = i >> 6, kk = i & 63;
            int r = rb + rr, k = kb + kk;
            tile[rr][kk] = (k < C) ? in[r * C + k] : 0.f;
        }
        __syncthreads();
        for (int i = tid; i < 4096; i += 256) {
            int kk = i >> 6, rr = i & 63;
            int k = kb + kk, r = rb + rr;
            if (k < Kpad) out[(size_t)k * HIDDEN + r] = tile[rr][kk];
        }
        return;
    }

    if (bid == 25) {
        for (int t = tid; t < 32 * 256; t += 256) {
            int k = t >> 8, j = t & 255;
            float v;
            if (j < 64)       v = Wq [j * 32 + k];
            else if (j < 128) v = Wk [(j - 64) * 32 + k];
            else if (j < 192) v = Wv [(j - 128) * 32 + k];
            else              v = Wsk[(j - 192) * 32 + k];
            Wall_t[t] = v;
        }
        if (tid < 64) {
            ball[tid]       = bq[tid];
            ball[64 + tid]  = bk[tid];
            ball[128 + tid] = bv[tid];
            ball[192 + tid] = bsk[tid];
        }
        return;
    }

    // ---- CSR build (bid 24)
    if (tid < N_NODES) cnt[tid] = 0;
    __syncthreads();
    for (int e = tid; e < N_EDGES; e += 256) atomicAdd(&cnt[ei[N_EDGES + e]], 1);
    __syncthreads();
    if (tid == 0) {
        int run = 0;
        for (int n = 0; n < N_NODES; ++n) { base[n] = run; run += cnt[n]; }
        base[N_NODES] = run;
    }
    __syncthreads();
    if (tid < N_NODES + 1) rp[tid] = base[tid];
    if (tid < N_NODES) cnt[tid] = base[tid];
    __syncthreads();
    for (int e = tid; e < N_EDGES; e += 256) {
        int d = ei[N_EDGES + e];
        int p = atomicAdd(&cnt[d], 1);
        csr_src[p] = ei[e];
        csr_dst[p] = d;
        csr_ew[p]  = ew[e];
    }
}

#define DOT4(S, Aa, Bb) S += Aa.x * Bb.x + Aa.y * Bb.y + Aa.z * Bb.z + Aa.w * Bb.w;

// ---------------------------------------------------------------------------
// K1: per-batch TransformerConv, fully fused. QKV GEMM from LDS-staged
// Wall_t (wave-uniform x broadcast, consecutive-f4 W reads); S = QK^T;
// owner softmax scans; A scatter; agg = A V. QKV-phase buffers (xs/Wall/ball)
// overlay the S/alpha region (dead before S-phase) in one union.
// ---------------------------------------------------------------------------
__global__ __launch_bounds__(512) void k1_conv(
    const float* __restrict__ state, const float* __restrict__ pos,
    const float* __restrict__ Wall_t, const float* __restrict__ ball,
    const int* __restrict__ rp_g, const int* __restrict__ csrc_g,
    const int* __restrict__ cdst_g, const float* __restrict__ cew_g,
    const float* __restrict__ We,
    float* __restrict__ out1_ws, float* __restrict__ ta_ws)
{
    __shared__ __align__(16) float qs [80 * 68];   // row 79 zero pad
    __shared__ __align__(16) float kss[80 * 68];
    __shared__ __align__(16) float vss[80 * 68];
    __shared__ __align__(16) float o1s[N_NODES * 68];
    // union: phase A = xs[79*32] | Wall_s[32*256] | ball_s[256]
    //        phase B = SA[80*80] | alpha[3000]
    __shared__ __align__(16) char uni[43904];
    __shared__ __align__(16) float ewc[N_EDGES];
    __shared__ unsigned short srcs[N_EDGES], dsts[N_EDGES];
    __shared__ __align__(16) float eW[64];
    __shared__ int   rp_s[80];
    __shared__ float qWe[80], csum_s[80];
    __shared__ float red80[80];

    float* xs     = (float*)uni;             // 10112 B
    float* Wall_s = (float*)(uni + 10112);   // 32768 B
    float* ball_s = (float*)(uni + 42880);   // 1024 B
    float* SA     = (float*)uni;             // 25600 B
    float* alpha  = (float*)(uni + 25600);   // 12000 B

    const int b = blockIdx.x, tid = threadIdx.x;

    // ---- P0: stage x, Wall, ball, edges, misc
    for (int t = tid; t < N_NODES * 32; t += 512) {
        int n = t >> 5, c = t & 31;
        xs[t] = (c < RAW_FEAT) ? state[(b * N_NODES + n) * RAW_FEAT + c]
                               : pos[n * 6 + (c - RAW_FEAT)];
    }
    {
        const float4* Wg4 = (const float4*)Wall_t;
        float4* Ws4w = (float4*)Wall_s;
        for (int t = tid; t < 2048; t += 512) Ws4w[t] = Wg4[t];
    }
    if (tid < 256) ball_s[tid] = ball[tid];
    for (int t = tid; t < N_EDGES; t += 512) {
        srcs[t] = (unsigned short)csrc_g[t];
        dsts[t] = (unsigned short)cdst_g[t];
        ewc[t]  = cew_g[t];
    }
    if (tid < 64) eW[tid] = We[tid];
    if (tid < 80) rp_s[tid] = rp_g[tid];
    if (tid < 79) red80[tid] = state[(b * N_NODES + tid) * RAW_FEAT + 1];
    if (tid == 79) red80[79] = 0.f;
    for (int t = tid; t < 68; t += 512) {          // zero pad row 79
        qs[79 * 68 + t] = 0.f; kss[79 * 68 + t] = 0.f; vss[79 * 68 + t] = 0.f;
    }
    __syncthreads();

    // ---- P1: QKV+skip GEMM: [79][256] = xs[79][32] @ Wall_s + ball.
    // Within a wave n is uniform (x broadcast); c4 = lane (consecutive f4 W).
    {
        const float4* xs4 = (const float4*)xs;
        const float4* W4  = (const float4*)Wall_s;
        const float4* b4  = (const float4*)ball_s;
        for (int t = tid; t < N_NODES * 64; t += 512) {
            int n = t >> 6, c4 = t & 63;
            float4 acc = b4[c4];
            #pragma unroll
            for (int k4 = 0; k4 < 8; ++k4) {
                float4 xv = xs4[n * 8 + k4];
                float4 w0 = W4[(k4 * 4 + 0) * 64 + c4];
                float4 w1 = W4[(k4 * 4 + 1) * 64 + c4];
                float4 w2 = W4[(k4 * 4 + 2) * 64 + c4];
                float4 w3 = W4[(k4 * 4 + 3) * 64 + c4];
                acc.x += xv.x * w0.x + xv.y * w1.x + xv.z * w2.x + xv.w * w3.x;
                acc.y += xv.x * w0.y + xv.y * w1.y + xv.z * w2.y + xv.w * w3.y;
                acc.z += xv.x * w0.z + xv.y * w1.z + xv.z * w2.z + xv.w * w3.z;
                acc.w += xv.x * w0.w + xv.y * w1.w + xv.z * w2.w + xv.w * w3.w;
            }
            if (c4 < 16)      ((float4*)qs )[n * 17 + c4]        = acc;
            else if (c4 < 32) ((float4*)kss)[n * 17 + (c4 - 16)] = acc;
            else if (c4 < 48) ((float4*)vss)[n * 17 + (c4 - 32)] = acc;
            else              ((float4*)o1s)[n * 17 + (c4 - 48)] = acc;
        }
    }
    __syncthreads();

    // ---- P2: ta reduction + qWe
    for (int off = 64; off >= 1; off >>= 1) {
        if (tid < off && tid + off < 80) red80[tid] += red80[tid + off];
        __syncthreads();
    }
    if (tid == 0) ta_ws[b] = red80[0];
    if (tid < N_NODES) {
        const float4* q4 = (const float4*)(qs + tid * 68);
        const float4* e4 = (const float4*)eW;
        float s = 0.f;
        #pragma unroll
        for (int i = 0; i < 16; ++i) {
            float4 a = q4[i], e = e4[i];
            DOT4(s, a, e)
        }
        qWe[tid] = s;
    }
    __syncthreads();   // also: xs/Wall dead beyond here -> SA may overwrite

    // ---- P3: dense S = Q K^T (5 rows x 3 cols per thread, named accums)
    {
        const int rg = tid >> 5, cgp = tid & 31;
        const int r0 = rg * 5;
        int c0 = cgp * 3; if (c0 > 76) c0 = 76;
        float s00 = 0, s01 = 0, s02 = 0;
        float s10 = 0, s11 = 0, s12 = 0;
        float s20 = 0, s21 = 0, s22 = 0;
        float s30 = 0, s31 = 0, s32 = 0;
        float s40 = 0, s41 = 0, s42 = 0;
        const float4* q4p = (const float4*)qs;
        const float4* k4p = (const float4*)kss;
        for (int k4 = 0; k4 < 16; ++k4) {
            float4 q0 = q4p[(r0 + 0) * 17 + k4];
            float4 q1 = q4p[(r0 + 1) * 17 + k4];
            float4 q2 = q4p[(r0 + 2) * 17 + k4];
            float4 q3 = q4p[(r0 + 3) * 17 + k4];
            float4 q4v = q4p[(r0 + 4) * 17 + k4];
            float4 c0v = k4p[(c0 + 0) * 17 + k4];
            float4 c1v = k4p[(c0 + 1) * 17 + k4];
            float4 c2v = k4p[(c0 + 2) * 17 + k4];
            DOT4(s00, q0, c0v)  DOT4(s01, q0, c1v)  DOT4(s02, q0, c2v)
            DOT4(s10, q1, c0v)  DOT4(s11, q1, c1v)  DOT4(s12, q1, c2v)
            DOT4(s20, q2, c0v)  DOT4(s21, q2, c1v)  DOT4(s22, q2, c2v)
            DOT4(s30, q3, c0v)  DOT4(s31, q3, c1v)  DOT4(s32, q3, c2v)
            DOT4(s40, q4v, c0v) DOT4(s41, q4v, c1v) DOT4(s42, q4v, c2v)
        }
        SA[(r0 + 0) * 80 + c0 + 0] = s00; SA[(r0 + 0) * 80 + c0 + 1] = s01; SA[(r0 + 0) * 80 + c0 + 2] = s02;
        SA[(r0 + 1) * 80 + c0 + 0] = s10; SA[(r0 + 1) * 80 + c0 + 1] = s11; SA[(r0 + 1) * 80 + c0 + 2] = s12;
        SA[(r0 + 2) * 80 + c0 + 0] = s20; SA[(r0 + 2) * 80 + c0 + 1] = s21; SA[(r0 + 2) * 80 + c0 + 2] = s22;
        SA[(r0 + 3) * 80 + c0 + 0] = s30; SA[(r0 + 3) * 80 + c0 + 1] = s31; SA[(r0 + 3) * 80 + c0 + 2] = s32;
        SA[(r0 + 4) * 80 + c0 + 0] = s40; SA[(r0 + 4) * 80 + c0 + 1] = s41; SA[(r0 + 4) * 80 + c0 + 2] = s42;
    }
    __syncthreads();

    // ---- P4: alpha per edge
    for (int t = tid; t < N_EDGES; t += 512) {
        int s = srcs[t], d = dsts[t];
        alpha[t] = 0.125f * (SA[d * 80 + s] + ewc[t] * qWe[d]);
    }
    __syncthreads();

    // ---- P5: zero SA for A accumulation
    for (int t = tid; t < 6400; t += 512) SA[t] = 0.f;
    __syncthreads();

    // ---- P6: per-node owner: max -> exp/den/csum -> A scatter
    if (tid < N_NODES) {
        int e0 = rp_s[tid], e1 = rp_s[tid + 1];
        float m = -1e30f;
        for (int e = e0; e < e1; ++e) m = fmaxf(m, alpha[e]);
        float s = 0.f, cs = 0.f;
        for (int e = e0; e < e1; ++e) {
            float ex = expf(alpha[e] - m);
            alpha[e] = ex;
            s += ex; cs += ex * ewc[e];
        }
        float rden = 1.f / (s + 1e-16f);
        csum_s[tid] = cs * rden;
        float* Ar = SA + tid * 80;
        for (int e = e0; e < e1; ++e) Ar[srcs[e]] += alpha[e] * rden;
    }
    __syncthreads();

    // ---- P7: dense agg = A V + epilogue
    {
        const int rowg = tid >> 4, colg = tid & 15;
        int n0 = rowg * 3; if (n0 > 76) n0 = 76;
        float4 g0 = {0.f, 0.f, 0.f, 0.f};
        float4 g1 = {0.f, 0.f, 0.f, 0.f};
        float4 g2 = {0.f, 0.f, 0.f, 0.f};
        const float4* A4  = (const float4*)SA;
        const float4* v4p = (const float4*)vss;

#define AGGSTEP(COMP, SS) { \
        float4 vv = v4p[(s4 * 4 + SS) * 17 + colg]; \
        g0.x += a0.COMP * vv.x; g0.y += a0.COMP * vv.y; g0.z += a0.COMP * vv.z; g0.w += a0.COMP * vv.w; \
        g1.x += a1.COMP * vv.x; g1.y += a1.COMP * vv.y; g1.z += a1.COMP * vv.z; g1.w += a1.COMP * vv.w; \
        g2.x += a2.COMP * vv.x; g2.y += a2.COMP * vv.y; g2.z += a2.COMP * vv.z; g2.w += a2.COMP * vv.w; }

        for (int s4 = 0; s4 < 20; ++s4) {
            float4 a0 = A4[(n0 + 0) * 20 + s4];
            float4 a1 = A4[(n0 + 1) * 20 + s4];
            float4 a2 = A4[(n0 + 2) * 20 + s4];
            AGGSTEP(x, 0)
            AGGSTEP(y, 1)
            AGGSTEP(z, 2)
            AGGSTEP(w, 3)
        }
#undef AGGSTEP

        const float4* o4 = (const float4*)o1s;
        const float4* e4 = (const float4*)eW;
        float4 ev = e4[colg];

#define AGGOUT(GI, I) { int n = n0 + I; if (n < N_NODES) { \
        float4 sk = o4[n * 17 + colg]; float cs = csum_s[n]; float4 r; \
        r.x = fmaxf(sk.x + GI.x + cs * ev.x, 0.f); \
        r.y = fmaxf(sk.y + GI.y + cs * ev.y, 0.f); \
        r.z = fmaxf(sk.z + GI.z + cs * ev.z, 0.f); \
        r.w = fmaxf(sk.w + GI.w + cs * ev.w, 0.f); \
        ((float4*)out1_ws)[((size_t)b * N_NODES + n) * 16 + colg] = r; } }

        AGGOUT(g0, 0)
        AGGOUT(g1, 1)
        AGGOUT(g2, 2)
#undef AGGOUT
    }
}

// ---------------------------------------------------------------------------
// K23: fused MLP. 632 blocks x 32 rows; thread = 4 rows x (4+4) cols.
// A1 overlays A2's buffer (A1 dead before LN1 writes) -> LDS 48 KB ->
// 3 blocks/CU, single-round makespan (768 slots >= 632 blocks).
// ---------------------------------------------------------------------------
__global__ __launch_bounds__(256) void k23_mlp(
    const float* __restrict__ state, const float* __restrict__ pos,
    const float* __restrict__ out1_ws, const float* __restrict__ ta_ws,
    const float* __restrict__ W1t, const float* __restrict__ b1,
    const float* __restrict__ g1, const float* __restrict__ be1,
    const float* __restrict__ W2t, const float* __restrict__ b2,
    const float* __restrict__ g2, const float* __restrict__ be2,
    const float* __restrict__ W3, const float* __restrict__ b3,
    float* __restrict__ conc_ws)
{
    __shared__ __align__(16) float A12[32 * 256];    // A1[32][112] then A2[32][256]
    __shared__ __align__(16) float Ws[16 * 256];     // 16 KB

    const int tid = threadIdx.x;
    const int cg = tid & 31;            // cols cg*4..+3 and 128+cg*4..+3
    const int rg = tid >> 5;            // rows rg*4..+3
    const int m0 = blockIdx.x * 32;

    const float4* W1t4 = (const float4*)W1t;
    const float4* W2t4 = (const float4*)W2t;
    const float4* A12_4 = (const float4*)A12;
    float4* Ws4w = (float4*)Ws;
    const float4* Ws4 = (const float4*)Ws;

    // ---- stage A1 [32][112] (into A12's first 14.3 KB)
    for (int t = tid; t < 32 * K1PAD; t += 256) {
        int r = t / K1PAD, k = t - r * K1PAD;
        int m = m0 + r;
        float v = 0.f;
        if (k < 64)       v = out1_ws[m * 64 + k];
        else if (k == 64) v = ta_ws[m / N_NODES];
        else if (k < 91)  v = state[m * RAW_FEAT + (k - 65)];
        else if (k < 97)  { int n = m - (m / N_NODES) * N_NODES;
                            v = pos[n * 6 + (k - 91)]; }
        A12[t] = v;
    }
    float4 pre0 = W1t4[tid];
    float4 pre1 = W1t4[tid + 256];
    float4 pre2 = W1t4[tid + 512];
    float4 pre3 = W1t4[tid + 768];
    __syncthreads();

    float4 accL0 = {0,0,0,0}, accL1 = {0,0,0,0}, accL2 = {0,0,0,0}, accL3 = {0,0,0,0};
    float4 accH0 = {0,0,0,0}, accH1 = {0,0,0,0}, accH2 = {0,0,0,0}, accH3 = {0,0,0,0};

#define KSTEP(COMP, KS) { \
    float4 wL = Ws4[(kq * 4 + KS) * 64 + cg]; \
    float4 wH = Ws4[(kq * 4 + KS) * 64 + 32 + cg]; \
    accL0.x += a0.COMP * wL.x; accL0.y += a0.COMP * wL.y; accL0.z += a0.COMP * wL.z; accL0.w += a0.COMP * wL.w; \
    accL1.x += a1.COMP * wL.x; accL1.y += a1.COMP * wL.y; accL1.z += a1.COMP * wL.z; accL1.w += a1.COMP * wL.w; \
    accL2.x += a2.COMP * wL.x; accL2.y += a2.COMP * wL.y; accL2.z += a2.COMP * wL.z; accL2.w += a2.COMP * wL.w; \
    accL3.x += a3.COMP * wL.x; accL3.y += a3.COMP * wL.y; accL3.z += a3.COMP * wL.z; accL3.w += a3.COMP * wL.w; \
    accH0.x += a0.COMP * wH.x; accH0.y += a0.COMP * wH.y; accH0.z += a0.COMP * wH.z; accH0.w += a0.COMP * wH.w; \
    accH1.x += a1.COMP * wH.x; accH1.y += a1.COMP * wH.y; accH1.z += a1.COMP * wH.z; accH1.w += a1.COMP * wH.w; \
    accH2.x += a2.COMP * wH.x; accH2.y += a2.COMP * wH.y; accH2.z += a2.COMP * wH.z; accH2.w += a2.COMP * wH.w; \
    accH3.x += a3.COMP * wH.x; accH3.y += a3.COMP * wH.y; accH3.z += a3.COMP * wH.z; accH3.w += a3.COMP * wH.w; }

    // ---- GEMM1: 7 chunks of K=16
    for (int ch = 0; ch < 7; ++ch) {
        Ws4w[tid] = pre0; Ws4w[tid + 256] = pre1;
        Ws4w[tid + 512] = pre2; Ws4w[tid + 768] = pre3;
        __syncthreads();
        if (ch < 6) {
            pre0 = W1t4[(ch + 1) * 1024 + tid];
            pre1 = W1t4[(ch + 1) * 1024 + tid + 256];
            pre2 = W1t4[(ch + 1) * 1024 + tid + 512];
            pre3 = W1t4[(ch + 1) * 1024 + tid + 768];
        } else {            // prefetch W2 chunk 0 (hides under LN1)
            pre0 = W2t4[tid];
            pre1 = W2t4[tid + 256];
            pre2 = W2t4[tid + 512];
            pre3 = W2t4[tid + 768];
        }
        #pragma unroll
        for (int kq = 0; kq < 4; ++kq) {
            float4 a0 = A12_4[(rg * 4 + 0) * 28 + ch * 4 + kq];
            float4 a1 = A12_4[(rg * 4 + 1) * 28 + ch * 4 + kq];
            float4 a2 = A12_4[(rg * 4 + 2) * 28 + ch * 4 + kq];
            float4 a3 = A12_4[(rg * 4 + 3) * 28 + ch * 4 + kq];
            KSTEP(x, 0)
            KSTEP(y, 1)
            KSTEP(z, 2)
            KSTEP(w, 3)
        }
        __syncthreads();    // final iteration: fences last A1 reads before LN1 writes
    }

    // ---- bias + LN1 + leaky -> A2 (overlays A1; safe past the barrier above)
    {
        float4 bL = ((const float4*)b1)[cg],  bH = ((const float4*)b1)[32 + cg];
        float4 gL = ((const float4*)g1)[cg],  gH = ((const float4*)g1)[32 + cg];
        float4 eL = ((const float4*)be1)[cg], eH = ((const float4*)be1)[32 + cg];

#define LN1_ROW(AL, AH, RR) { \
        float v0 = AL.x + bL.x, v1 = AL.y + bL.y, v2 = AL.z + bL.z, v3 = AL.w + bL.w; \
        float v4 = AH.x + bH.x, v5 = AH.y + bH.y, v6 = AH.z + bH.z, v7 = AH.w + bH.w; \
        float sm = v0 + v1 + v2 + v3 + v4 + v5 + v6 + v7; \
        float sq = v0*v0 + v1*v1 + v2*v2 + v3*v3 + v4*v4 + v5*v5 + v6*v6 + v7*v7; \
        for (int off = 16; off >= 1; off >>= 1) { sm += __shfl_xor(sm, off, 64); sq += __shfl_xor(sq, off, 64); } \
        float mu = sm * (1.f / 256.f), rstd = rsqrtf(sq * (1.f / 256.f) - mu * mu + 1e-5f); \
        float4 yL, yH; \
        yL.x = (v0 - mu) * rstd * gL.x + eL.x; yL.y = (v1 - mu) * rstd * gL.y + eL.y; \
        yL.z = (v2 - mu) * rstd * gL.z + eL.z; yL.w = (v3 - mu) * rstd * gL.w + eL.w; \
        yH.x = (v4 - mu) * rstd * gH.x + eH.x; yH.y = (v5 - mu) * rstd * gH.y + eH.y; \
        yH.z = (v6 - mu) * rstd * gH.z + eH.z; yH.w = (v7 - mu) * rstd * gH.w + eH.w; \
        yL.x = yL.x > 0.f ? yL.x : 0.01f * yL.x; yL.y = yL.y > 0.f ? yL.y : 0.01f * yL.y; \
        yL.z = yL.z > 0.f ? yL.z : 0.01f * yL.z; yL.w = yL.w > 0.f ? yL.w : 0.01f * yL.w; \
        yH.x = yH.x > 0.f ? yH.x : 0.01f * yH.x; yH.y = yH.y > 0.f ? yH.y : 0.01f * yH.y; \
        yH.z = yH.z > 0.f ? yH.z : 0.01f * yH.z; yH.w = yH.w > 0.f ? yH.w : 0.01f * yH.w; \
        ((float4*)A12)[(rg * 4 + RR) * 64 + cg] = yL; \
        ((float4*)A12)[(rg * 4 + RR) * 64 + 32 + cg] = yH; }

        LN1_ROW(accL0, accH0, 0)
        LN1_ROW(accL1, accH1, 1)
        LN1_ROW(accL2, accH2, 2)
        LN1_ROW(accL3, accH3, 3)
#undef LN1_ROW
        accL0 = {0,0,0,0}; accL1 = {0,0,0,0}; accL2 = {0,0,0,0}; accL3 = {0,0,0,0};
        accH0 = {0,0,0,0}; accH1 = {0,0,0,0}; accH2 = {0,0,0,0}; accH3 = {0,0,0,0};
    }

    // ---- GEMM2: 16 chunks of K=16 (chunk-0 barrier fences A2 writes)
    for (int ch = 0; ch < 16; ++ch) {
        Ws4w[tid] = pre0; Ws4w[tid + 256] = pre1;
        Ws4w[tid + 512] = pre2; Ws4w[tid + 768] = pre3;
        __syncthreads();
        if (ch < 15) {
            pre0 = W2t4[(ch + 1) * 1024 + tid];
            pre1 = W2t4[(ch + 1) * 1024 + tid + 256];
            pre2 = W2t4[(ch + 1) * 1024 + tid + 512];
            pre3 = W2t4[(ch + 1) * 1024 + tid + 768];
        }
        #pragma unroll
        for (int kq = 0; kq < 4; ++kq) {
            float4 a0 = A12_4[(rg * 4 + 0) * 64 + ch * 4 + kq];
            float4 a1 = A12_4[(rg * 4 + 1) * 64 + ch * 4 + kq];
            float4 a2 = A12_4[(rg * 4 + 2) * 64 + ch * 4 + kq];
            float4 a3 = A12_4[(rg * 4 + 3) * 64 + ch * 4 + kq];
            KSTEP(x, 0)
            KSTEP(y, 1)
            KSTEP(z, 2)
            KSTEP(w, 3)
        }
        __syncthreads();
    }
#undef KSTEP

    // ---- bias + LN2 + leaky + W3 dot + softplus
    {
        float4 bL = ((const float4*)b2)[cg],  bH = ((const float4*)b2)[32 + cg];
        float4 gL = ((const float4*)g2)[cg],  gH = ((const float4*)g2)[32 + cg];
        float4 eL = ((const float4*)be2)[cg], eH = ((const float4*)be2)[32 + cg];
        float4 wL3 = ((const float4*)W3)[cg], wH3 = ((const float4*)W3)[32 + cg];
        float bb3 = b3[0];

#define LN2_ROW(AL, AH, RR) { \
        float v0 = AL.x + bL.x, v1 = AL.y + bL.y, v2 = AL.z + bL.z, v3 = AL.w + bL.w; \
        float v4 = AH.x + bH.x, v5 = AH.y + bH.y, v6 = AH.z + bH.z, v7 = AH.w + bH.w; \
        float sm = v0 + v1 + v2 + v3 + v4 + v5 + v6 + v7; \
        float sq = v0*v0 + v1*v1 + v2*v2 + v3*v3 + v4*v4 + v5*v5 + v6*v6 + v7*v7; \
        for (int off = 16; off >= 1; off >>= 1) { sm += __shfl_xor(sm, off, 64); sq += __shfl_xor(sq, off, 64); } \
        float mu = sm * (1.f / 256.f), rstd = rsqrtf(sq * (1.f / 256.f) - mu * mu + 1e-5f); \
        float z0 = (v0 - mu) * rstd * gL.x + eL.x, z1 = (v1 - mu) * rstd * gL.y + eL.y; \
        float z2 = (v2 - mu) * rstd * gL.z + eL.z, z3 = (v3 - mu) * rstd * gL.w + eL.w; \
        float z4 = (v4 - mu) * rstd * gH.x + eH.x, z5 = (v5 - mu) * rstd * gH.y + eH.y; \
        float z6 = (v6 - mu) * rstd * gH.z + eH.z, z7 = (v7 - mu) * rstd * gH.w + eH.w; \
        z0 = z0 > 0.f ? z0 : 0.01f * z0; z1 = z1 > 0.f ? z1 : 0.01f * z1; \
        z2 = z2 > 0.f ? z2 : 0.01f * z2; z3 = z3 > 0.f ? z3 : 0.01f * z3; \
        z4 = z4 > 0.f ? z4 : 0.01f * z4; z5 = z5 > 0.f ? z5 : 0.01f * z5; \
        z6 = z6 > 0.f ? z6 : 0.01f * z6; z7 = z7 > 0.f ? z7 : 0.01f * z7; \
        float part = z0 * wL3.x + z1 * wL3.y + z2 * wL3.z + z3 * wL3.w \
                   + z4 * wH3.x + z5 * wH3.y + z6 * wH3.z + z7 * wH3.w; \
        for (int off = 16; off >= 1; off >>= 1) part += __shfl_xor(part, off, 64); \
        if (cg == 0) { float x = part + bb3; \
            conc_ws[m0 + rg * 4 + RR] = fmaxf(x, 0.f) + log1pf(expf(-fabsf(x))); } }

        LN2_ROW(accL0, accH0, 0)
        LN2_ROW(accL1, accH1, 1)
        LN2_ROW(accL2, accH2, 2)
        LN2_ROW(accL3, accH3, 3)
#undef LN2_ROW
    }
}

// ---------------------------------------------------------------------------
// K4: action = conc / (sum_n conc + 1e-20), per batch
// ---------------------------------------------------------------------------
__global__ __launch_bounds__(128) void k4_norm(
    const float* __restrict__ conc_ws, float* __restrict__ out)
{
    __shared__ float red[128];
    const int b = blockIdx.x, tid = threadIdx.x;
    float v = 0.f;
    if (tid < N_NODES) v = conc_ws[b * N_NODES + tid];
    red[tid] = v;
    __syncthreads();
    for (int off = 64; off >= 1; off >>= 1) {
        if (tid < off) red[tid] += red[tid + off];
        __syncthreads();
    }
    float s = red[0];
    if (tid < N_NODES) out[b * N_NODES + tid] = v / (s + 1e-20f);
}

extern "C" void kernel_launch(void* const* d_in, const int* in_sizes, int n_in,
                              void* d_out, int out_size, void* d_ws, size_t ws_size,
                              hipStream_t stream) {
    const float* state = (const float*)d_in[0];
    const float* pos   = (const float*)d_in[1];
    const float* ew    = (const float*)d_in[2];
    const float* Wq  = (const float*)d_in[3];  const float* bq  = (const float*)d_in[4];
    const float* Wk  = (const float*)d_in[5];  const float* bk  = (const float*)d_in[6];
    const float* Wv  = (const float*)d_in[7];  const float* bv  = (const float*)d_in[8];
    const float* We  = (const float*)d_in[9];
    const float* Wsk = (const float*)d_in[10]; const float* bsk = (const float*)d_in[11];
    const float* W1  = (const float*)d_in[12]; const float* b1  = (const float*)d_in[13];
    const float* g1  = (const float*)d_in[14]; const float* be1 = (const float*)d_in[15];
    const float* W2  = (const float*)d_in[16]; const float* b2  = (const float*)d_in[17];
    const float* g2  = (const float*)d_in[18]; const float* be2 = (const float*)d_in[19];
    const float* W3  = (const float*)d_in[20]; const float* b3  = (const float*)d_in[21];
    const int*   ei  = (const int*)d_in[22];

    float* ws    = (float*)d_ws;
    float* ta    = ws;                                  // 256
    float* out1  = ws + 256;                            // M*64
    float* conc  = out1 + (size_t)M_ROWS * 64;          // M
    float* W1t   = conc + M_ROWS;                       // 112*256
    float* W2t   = W1t + K1PAD * HIDDEN;                // 256*256
    float* Wall  = W2t + HIDDEN * HIDDEN;               // 32*256
    float* ball  = Wall + 32 * 256;                     // 256
    int*   rp    = (int*)(ball + 256);                  // 80
    int*   csrc  = rp + 80;                             // 3000
    int*   cdst  = csrc + N_EDGES;                      // 3000
    float* cew   = (float*)(cdst + N_EDGES);            // 3000
    float* out   = (float*)d_out;

    k_prep<<<dim3(26), dim3(256), 0, stream>>>(
        W1, W2, ei, ew, Wq, Wk, Wv, Wsk, bq, bk, bv, bsk,
        W1t, W2t, Wall, ball, rp, csrc, cdst, cew);
    k1_conv<<<dim3(BATCH), dim3(512), 0, stream>>>(
        state, pos, Wall, ball, rp, csrc, cdst, cew, We, out1, ta);
    k23_mlp<<<dim3(M_ROWS / 32), dim3(256), 0, stream>>>(
        state, pos, out1, ta, W1t, b1, g1, be1,
        W2t, b2, g2, be2, W3, b3, conc);
    k4_norm<<<dim3(BATCH), dim3(128), 0, stream>>>(conc, out);
}